// Round 2
// baseline (20698.526 us; speedup 1.0000x reference)
//
#include <hip/hip_runtime.h>
#include <hip/hip_bf16.h>

// Problem constants
constexpr int BB = 128;   // batch
constexpr int TPp = 128;  // premise len
constexpr int THh = 64;   // hypothesis len
constexpr int HH = 512;   // hidden

// ---------------- workspace layout (fp32 words), total ~110.6 MB + 2KB ----------------
constexpr size_t OFF_HS     = 0;                               // [128][128][512]
constexpr size_t SZ_HS      = (size_t)16384 * 512;
constexpr size_t OFF_HT     = OFF_HS + SZ_HS;                  // [128][64][512]
constexpr size_t SZ_HT      = (size_t)8192 * 512;
constexpr size_t OFF_WSM    = OFF_HT + SZ_HT;                  // Ws [16384][512] (match phase)
constexpr size_t SZ_WSM     = (size_t)16384 * 512;
// During LSTM phase WSM is dead -> xg scratch (16-step chunks)
constexpr size_t OFF_XG_P   = OFF_WSM;                         // [16 tl][128 li][128 b][16 slot]
constexpr size_t OFF_XG_H   = OFF_WSM + (size_t)16 * 128 * 128 * 16;
constexpr size_t OFF_WIHT_P = OFF_WSM + SZ_WSM;                // [304][2048] (rows 300-302 zero, 303 = bih+bhh)
constexpr size_t SZ_WIHT    = (size_t)304 * 2048;
constexpr size_t OFF_WIHT_H = OFF_WIHT_P + SZ_WIHT;
constexpr size_t OFF_WHHT_P = OFF_WIHT_H + SZ_WIHT;            // WSTK_P: [128 li][512 k][16 c] c=jj*4+g
constexpr size_t OFF_WHHT_H = OFF_WHHT_P + (size_t)512 * 2048; // WSTK_H
constexpr size_t OFF_WB1T   = OFF_WHHT_H + (size_t)512 * 2048; // [2560 c][1024 k] transposed P1 weights
constexpr size_t OFF_WIA    = OFF_WB1T + (size_t)2560 * 1024;  // [512 k][j*4+g]  Wih_m[:, :512]
constexpr size_t OFF_WEF    = OFF_WIA + (size_t)512 * 2048;    // w_e fp32 [512]
constexpr size_t OFF_BM     = OFF_WEF + 512;                   // bih_m+bhh_m [2048]
constexpr size_t OFF_HC_P   = OFF_BM + 2048;                   // 2 x [128][512] h carry dbuf (premise)
constexpr size_t OFF_HC_H   = OFF_HC_P + 2 * (size_t)BB * HH;  // 2 x [128][512] (hyp)
constexpr size_t OFF_C_P    = OFF_HC_H + 2 * (size_t)BB * HH;  // (vestigial, kept zeroed)
constexpr size_t OFF_C_H    = OFF_C_P + (size_t)BB * HH;
constexpr size_t OFF_Q      = OFF_C_H + (size_t)BB * HH;       // [128][512]
constexpr size_t OFF_GH     = OFF_Q + (size_t)BB * HH;         // ghp [128][2048] PACKED j*4+g
constexpr size_t OFF_A      = OFF_GH + (size_t)BB * 2048;      // [128][512]
constexpr size_t OFF_HM     = OFF_A + (size_t)BB * HH;         // [128][512]
constexpr size_t OFF_CM     = OFF_HM + (size_t)BB * HH;        // (vestigial, kept zeroed)
constexpr size_t OFF_LAST   = OFF_CM + (size_t)BB * HH;        // [128][512]
constexpr size_t OFF_CNT    = OFF_LAST + (size_t)BB * HH;      // 512 barrier counters (uint)
constexpr size_t WS_FLOATS  = OFF_CNT + 512;

__device__ __forceinline__ float sigmf(float x) { return 1.0f / (1.0f + __expf(-x)); }
__device__ __forceinline__ float tanh_f(float x) {
  float e = __expf(-2.0f * fabsf(x));
  float r = (1.0f - e) / (1.0f + e);
  return copysignf(r, x);
}

// ---- grid barrier: unique counter per event, zeroed by k_prep each call (replay-safe) ----
__device__ __forceinline__ void gbar(float* ws, int idx) {
  __syncthreads();
  if (threadIdx.x == 0) {
    unsigned* cnt = (unsigned*)(ws + OFF_CNT) + idx;
    __threadfence();
    __hip_atomic_fetch_add(cnt, 1u, __ATOMIC_RELAXED, __HIP_MEMORY_SCOPE_AGENT);
    while (__hip_atomic_load(cnt, __ATOMIC_RELAXED, __HIP_MEMORY_SCOPE_AGENT) < 256u)
      __builtin_amdgcn_s_sleep(2);
    __threadfence();
  }
  __syncthreads();
}

// ---------------- diag ----------------
__global__ void k_diag(float* out, float v) {
  int i = blockIdx.x * 64 + threadIdx.x;
  if (i < BB * 3) out[i] = v;
}

// ---------------- K0: weight transpose/stack + state/counter zero ----------------
__global__ __launch_bounds__(256) void k_prep(float* ws,
    const float* Wih_p, const float* bih_p, const float* bhh_p,
    const float* Wih_h, const float* bih_h, const float* bhh_h,
    const float* Whh_p, const float* Whh_h,
    const float* Whh_m, const float* Wih_m, const float* bih_m, const float* bhh_m,
    const float* W_m, const float* W_t, const float* w_e) {
  size_t gid = (size_t)blockIdx.x * 256 + threadIdx.x;
  if (gid < SZ_WIHT) {
    int k = (int)(gid >> 11), r = (int)(gid & 2047);
    float v = (k < 300) ? Wih_p[(size_t)r * 300 + k]
            : (k == 303) ? (bih_p[r] + bhh_p[r]) : 0.f;
    ws[OFF_WIHT_P + gid] = v;
    return;
  }
  gid -= SZ_WIHT;
  if (gid < SZ_WIHT) {
    int k = (int)(gid >> 11), r = (int)(gid & 2047);
    float v = (k < 300) ? Wih_h[(size_t)r * 300 + k]
            : (k == 303) ? (bih_h[r] + bhh_h[r]) : 0.f;
    ws[OFF_WIHT_H + gid] = v;
    return;
  }
  gid -= SZ_WIHT;
  const size_t NT = (size_t)512 * 2048;
  if (gid < NT) {  // WSTK_P [li][k][16]: c=jj*4+g -> Whh row g*512+li*4+jj, col k
    int li = (int)(gid >> 13);
    int rem = (int)(gid & 8191);
    int k = rem >> 4, c = rem & 15;
    int jj = c >> 2, g = c & 3;
    ws[OFF_WHHT_P + gid] = Whh_p[(size_t)(g * 512 + li * 4 + jj) * 512 + k];
    return;
  }
  gid -= NT;
  if (gid < NT) {  // WSTK_H
    int li = (int)(gid >> 13);
    int rem = (int)(gid & 8191);
    int k = rem >> 4, c = rem & 15;
    int jj = c >> 2, g = c & 3;
    ws[OFF_WHHT_H + gid] = Whh_h[(size_t)(g * 512 + li * 4 + jj) * 512 + k];
    return;
  }
  gid -= NT;
  if (gid < (size_t)2560 * 1024) {  // WB1T [c][k]
    int c = (int)(gid >> 10), k = (int)(gid & 1023);
    float v;
    if (c < 512) {
      v = (k < 512) ? W_m[(size_t)c * 512 + k] : W_t[(size_t)c * 512 + (k - 512)];
    } else {
      int p = c - 512;
      int j = p >> 2, g = p & 3;
      int r = g * 512 + j;
      v = (k < 512) ? Whh_m[(size_t)r * 512 + k] : Wih_m[(size_t)r * 1024 + k];
    }
    ws[OFF_WB1T + gid] = v;
    return;
  }
  gid -= (size_t)2560 * 1024;
  if (gid < NT) {  // WIA [k][j*4+g]
    int k = (int)(gid >> 11), c = (int)(gid & 2047);
    int j = c >> 2, g = c & 3;
    ws[OFF_WIA + gid] = Wih_m[((size_t)g * 512 + j) * 1024 + k];
    return;
  }
  gid -= NT;
  if (gid < 512) { ws[OFF_WEF + gid] = w_e[gid]; return; }
  gid -= 512;
  if (gid < 2048) { ws[OFF_BM + gid] = bih_m[gid] + bhh_m[gid]; return; }
  gid -= 2048;
  if (gid < (size_t)393216) { ws[OFF_HC_P + gid] = 0.f; return; }  // HC_P,HC_H,C_P,C_H
  gid -= 393216;
  if (gid < (size_t)131072) { ws[OFF_HM + gid] = 0.f; return; }    // HM, CM
  gid -= 131072;
  if (gid < 512) { ws[OFF_CNT + gid] = 0.f; return; }              // barrier counters
}

// ---------------- generic 64x64-tile fp32 GEMM (Ws = HS @ W_s^T) ----------------
__global__ __launch_bounds__(256) void k_gemm(const float* __restrict__ A,
                                              const float* __restrict__ Bw, int ldb, int Kdim,
                                              int N, float* __restrict__ C, int ntilesN) {
  __shared__ float As[16][68];
  __shared__ float Bs[16][68];
  const int tid = threadIdx.x;
  const int bid = blockIdx.x;
  const int tm = bid / ntilesN, tn = bid % ntilesN;
  const int m0 = tm * 64, n0 = tn * 64;
  const int tx = tid & 15, ty = tid >> 4;
  const int srow = tid >> 2, skc = (tid & 3) * 4;
  float acc[4][4] = {};
  const float* arowf = A + (size_t)(m0 + srow) * Kdim;
  const float* brow = Bw + (size_t)(n0 + srow) * ldb;
  for (int k0 = 0; k0 < Kdim; k0 += 16) {
    float4 v = *(const float4*)(arowf + k0 + skc);
    As[skc + 0][srow] = v.x; As[skc + 1][srow] = v.y;
    As[skc + 2][srow] = v.z; As[skc + 3][srow] = v.w;
#pragma unroll
    for (int i = 0; i < 4; i++) Bs[skc + i][srow] = brow[k0 + skc + i];
    __syncthreads();
#pragma unroll
    for (int kk = 0; kk < 16; kk++) {
      float4 a4 = *(float4*)&As[kk][ty * 4];
      float4 b4 = *(float4*)&Bs[kk][tx * 4];
      acc[0][0] += a4.x * b4.x; acc[0][1] += a4.x * b4.y; acc[0][2] += a4.x * b4.z; acc[0][3] += a4.x * b4.w;
      acc[1][0] += a4.y * b4.x; acc[1][1] += a4.y * b4.y; acc[1][2] += a4.y * b4.z; acc[1][3] += a4.y * b4.w;
      acc[2][0] += a4.z * b4.x; acc[2][1] += a4.z * b4.y; acc[2][2] += a4.z * b4.z; acc[2][3] += a4.z * b4.w;
      acc[3][0] += a4.w * b4.x; acc[3][1] += a4.w * b4.y; acc[3][2] += a4.w * b4.z; acc[3][3] += a4.w * b4.w;
    }
    __syncthreads();
  }
  const int m = m0 + ty * 4, n = n0 + tx * 4;
#pragma unroll
  for (int i = 0; i < 4; i++) {
    float4 o = {acc[i][0], acc[i][1], acc[i][2], acc[i][3]};
    *(float4*)&C[(size_t)(m + i) * N + n] = o;
  }
}

// ---------------- persistent LSTM mega-kernel: all 128 steps + inline xg chunks ----------------
__global__ __launch_bounds__(256) void k_lstm_mega(float* __restrict__ ws,
    const int* __restrict__ premise, const int* __restrict__ hyp,
    const int* __restrict__ plen, const int* __restrict__ hlen,
    const float* __restrict__ emb) {
  __shared__ float4 smem4[4096];           // 64 KB
  float4* wlds4 = smem4;                   // [512 k][4 cg]
  float4* hbuf4 = smem4 + 2048;            // [128 b][16 k4] swizzled
  float* xAs = (float*)(smem4 + 2048);     // xg alias: [16][68]
  float* xBs = xAs + 16 * 68;
  int* xTok = (int*)(xBs + 16 * 68);

  const int tid = threadIdx.x;
  const int bid = blockIdx.x;
  const int seq = bid >> 7;
  const int li = bid & 127;
  const int T = seq ? THh : TPp;
  const int* lens = seq ? hlen : plen;
  const float* wstk = ws + (seq ? OFF_WHHT_H : OFF_WHHT_P) + (size_t)li * 8192;
  float* hsout = ws + (seq ? OFF_HT : OFF_HS);
  float* hc = ws + (seq ? OFF_HC_H : OFF_HC_P);

  // stage Whh slice once (persists across all steps)
  {
    const float4* src = (const float4*)wstk;
#pragma unroll
    for (int j2 = 0; j2 < 8; j2++) wlds4[tid + j2 * 256] = src[tid + j2 * 256];
  }
  const int bg = tid & 63, cg = tid >> 6;
  const int b0 = 2 * bg, b1 = 2 * bg + 1;
  const int sw = bg & 7;
  const int jcol = li * 4 + cg;
  const int len0 = lens[b0], len1 = lens[b1];
  float c0r = 0.f, c1r = 0.f, h0r = 0.f, h1r = 0.f;
  int bi = 0;

  for (int t = 0; t < TPp; t++) {
    if ((t & 15) == 0) {
      // ---- inline xg chunk GEMM (tiles 64x64, K=304) ----
      int ntl = (t < THh) ? 2048 : 1024;
      __syncthreads();
      for (int tile = bid; tile < ntl; tile += 256) {
        const int seqx = tile >> 10;
        const int u = tile & 1023;
        const int tm = u >> 5, tn = u & 31;
        const int m0 = tm * 64, n0 = tn * 64;
        const int Tx = seqx ? THh : TPp;
        const int* toks = seqx ? hyp : premise;
        const float* WX = ws + (seqx ? OFF_WIHT_H : OFF_WIHT_P);
        float* xg = ws + (seqx ? OFF_XG_H : OFF_XG_P);
        if (tid < 64) {
          int r = m0 + tid;
          int tl = r >> 7, b = r & 127;
          xTok[tid] = toks[(size_t)b * Tx + t + tl];
        }
        __syncthreads();
        const int tx = tid & 15, ty = tid >> 4;
        const int sr = tid & 63, sk0 = (tid >> 6) * 4;
        const int bky = tid >> 4, bkx = (tid & 15) * 4;
        float acc[4][4] = {};
        for (int k0 = 0; k0 < 304; k0 += 16) {
          int tok = xTok[sr];
#pragma unroll
          for (int i = 0; i < 4; i++) {
            int kx = k0 + sk0 + i;
            float v = 0.f;
            if (kx < 300) v = emb[(size_t)tok * 300 + kx];
            else if (kx == 303) v = 1.0f;  // bias-one row
            xAs[(sk0 + i) * 68 + sr] = v;
          }
          *(float4*)&xBs[bky * 68 + bkx] = *(const float4*)(WX + (size_t)(k0 + bky) * 2048 + n0 + bkx);
          __syncthreads();
#pragma unroll
          for (int kk = 0; kk < 16; kk++) {
            float4 a4 = *(float4*)&xAs[kk * 68 + ty * 4];
            float4 b4 = *(float4*)&xBs[kk * 68 + tx * 4];
            acc[0][0] += a4.x * b4.x; acc[0][1] += a4.x * b4.y; acc[0][2] += a4.x * b4.z; acc[0][3] += a4.x * b4.w;
            acc[1][0] += a4.y * b4.x; acc[1][1] += a4.y * b4.y; acc[1][2] += a4.y * b4.z; acc[1][3] += a4.y * b4.w;
            acc[2][0] += a4.z * b4.x; acc[2][1] += a4.z * b4.y; acc[2][2] += a4.z * b4.z; acc[2][3] += a4.z * b4.w;
            acc[3][0] += a4.w * b4.x; acc[3][1] += a4.w * b4.y; acc[3][2] += a4.w * b4.z; acc[3][3] += a4.w * b4.w;
          }
          __syncthreads();
        }
        const int cbase = n0 + tx * 4;
        const int g = cbase >> 9;
        const int li2 = (cbase & 511) >> 2;
#pragma unroll
        for (int i = 0; i < 4; i++) {
          int r = m0 + ty * 4 + i;
          int tl = r >> 7, b = r & 127;
          float* dst = xg + (((size_t)tl * 128 + li2) * 128 + b) * 16 + g;
#pragma unroll
          for (int jj = 0; jj < 4; jj++) dst[jj * 4] = acc[i][jj];
        }
      }
      gbar(ws, bi);
      bi++;
    }
    const int par = t & 1;
    const bool active = !(seq && t >= THh);
    if (active) {
      const float* hin = hc + (size_t)par * (BB * HH);
      float* hout = hc + (size_t)(par ^ 1) * (BB * HH);
      const float* xgp = ws + (seq ? OFF_XG_H : OFF_XG_P) + ((size_t)(t & 15) * 128 + li) * 2048;
      float4 acc0 = {0.f, 0.f, 0.f, 0.f}, acc1 = {0.f, 0.f, 0.f, 0.f};
      float4 pre[8];
#pragma unroll
      for (int j2 = 0; j2 < 8; j2++) {
        int fi = tid + j2 * 256, b = fi >> 4, k4 = fi & 15;
        pre[j2] = *(const float4*)(hin + (size_t)b * 512 + k4 * 4);
      }
      for (int kc = 0; kc < 512; kc += 64) {
        __syncthreads();
#pragma unroll
        for (int j2 = 0; j2 < 8; j2++) {
          int fi = tid + j2 * 256, b = fi >> 4, k4 = fi & 15;
          hbuf4[b * 16 + (k4 ^ ((b >> 1) & 7))] = pre[j2];
        }
        __syncthreads();
        if (kc + 64 < 512) {
#pragma unroll
          for (int j2 = 0; j2 < 8; j2++) {
            int fi = tid + j2 * 256, b = fi >> 4, k4 = fi & 15;
            pre[j2] = *(const float4*)(hin + (size_t)b * 512 + (kc + 64) + k4 * 4);
          }
        }
#pragma unroll
        for (int kk = 0; kk < 64; kk += 4) {
          int k4 = kk >> 2;
          float4 h0 = hbuf4[b0 * 16 + (k4 ^ sw)];
          float4 h1 = hbuf4[b1 * 16 + (k4 ^ sw)];
          float4 w0 = wlds4[(kc + kk + 0) * 4 + cg];
          float4 w1 = wlds4[(kc + kk + 1) * 4 + cg];
          float4 w2 = wlds4[(kc + kk + 2) * 4 + cg];
          float4 w3 = wlds4[(kc + kk + 3) * 4 + cg];
          acc0.x += h0.x * w0.x + h0.y * w1.x + h0.z * w2.x + h0.w * w3.x;
          acc0.y += h0.x * w0.y + h0.y * w1.y + h0.z * w2.y + h0.w * w3.y;
          acc0.z += h0.x * w0.z + h0.y * w1.z + h0.z * w2.z + h0.w * w3.z;
          acc0.w += h0.x * w0.w + h0.y * w1.w + h0.z * w2.w + h0.w * w3.w;
          acc1.x += h1.x * w0.x + h1.y * w1.x + h1.z * w2.x + h1.w * w3.x;
          acc1.y += h1.x * w0.y + h1.y * w1.y + h1.z * w2.y + h1.w * w3.y;
          acc1.z += h1.x * w0.z + h1.y * w1.z + h1.z * w2.z + h1.w * w3.z;
          acc1.w += h1.x * w0.w + h1.y * w1.w + h1.z * w2.w + h1.w * w3.w;
        }
      }
      float4 x0 = *(const float4*)(xgp + (size_t)b0 * 16 + cg * 4);
      float4 x1 = *(const float4*)(xgp + (size_t)b1 * 16 + cg * 4);
      {
        float iv = sigmf(acc0.x + x0.x), fv = sigmf(acc0.y + x0.y);
        float gv = tanh_f(acc0.z + x0.z), ov = sigmf(acc0.w + x0.w);
        float cn = fv * c0r + iv * gv;
        float hn = ov * tanh_f(cn);
        bool inr = t < len0;
        if (inr) { c0r = cn; h0r = hn; }
        hsout[((size_t)b0 * T + t) * 512 + jcol] = inr ? hn : 0.f;
        hout[(size_t)b0 * 512 + jcol] = h0r;
      }
      {
        float iv = sigmf(acc1.x + x1.x), fv = sigmf(acc1.y + x1.y);
        float gv = tanh_f(acc1.z + x1.z), ov = sigmf(acc1.w + x1.w);
        float cn = fv * c1r + iv * gv;
        float hn = ov * tanh_f(cn);
        bool inr = t < len1;
        if (inr) { c1r = cn; h1r = hn; }
        hsout[((size_t)b1 * T + t) * 512 + jcol] = inr ? hn : 0.f;
        hout[(size_t)b1 * 512 + jcol] = h1r;
      }
    }
    gbar(ws, bi);
    bi++;
  }
}

// ---------------- persistent match mega-kernel: 64 steps x {P1,P2,P3} ----------------
__global__ __launch_bounds__(256) void k_match_mega(float* __restrict__ ws,
                                                    const int* __restrict__ hlen) {
  __shared__ float smem[16384];  // 64 KB exactly
  float* B1 = smem;              // [10 c][1024 k]  P1 weight slice (persistent)
  float* W3 = smem + 10240;      // [8 c][512 k]    P3 weight slice (persistent)
  float* AL = smem + 14336;      // [16 k][128 b]   A-chunk staging (2048 floats)
  // P2 aliases inside AL region:
  float* q_lds = AL; float* we_lds = AL + 512; float* e_part = AL + 1024;
  float* e_lds = AL + 1280; float* alpha_lds = AL + 1408; float* red_s = AL + 1536;

  const int tid = threadIdx.x;
  const int bid = blockIdx.x;
  float* hm = ws + OFF_HM;
  const float* ht = ws + OFF_HT;
  float* qbuf = ws + OFF_Q;
  float* ghp = ws + OFF_GH;
  float* abuf = ws + OFF_A;
  float* last = ws + OFF_LAST;

  // stage persistent weight slices
  {
    const float* wb1t = ws + OFF_WB1T + (size_t)bid * 10 * 1024;
    for (int i = tid; i < 10 * 1024; i += 256) {
      int cc = i >> 10, kk2 = i & 1023;
      B1[cc * 1024 + kk2] = wb1t[(size_t)cc * 1024 + kk2];
    }
    const float* wia = ws + OFF_WIA;
    for (int i = tid; i < 8 * 512; i += 256) {
      int cc = i >> 9, kk2 = i & 511;
      W3[cc * 512 + kk2] = wia[(size_t)kk2 * 2048 + bid * 8 + cc];
    }
  }
  const int r = tid >> 1, half = tid & 1;
  const int jj = half;
  const int j3 = bid * 2 + jj;           // P3 hidden col owned by this thread
  float c_reg = 0.f;                      // match-cell c state, register resident
  float bmp[4];
#pragma unroll
  for (int g = 0; g < 4; g++) bmp[g] = ws[OFF_BM + g * 512 + j3];
  const int hl = hlen[r];
  int bi = 200;  // match kernel's counter range
  __syncthreads();

  for (int k = 0; k < THh; k++) {
    // ---------- P1: q + ghp = [hm | htk] @ WB1T (block owns 10 cols) ----------
    {
      float acc1[5] = {0.f, 0.f, 0.f, 0.f, 0.f};
      const int f0 = tid, f1 = tid + 256;
      const int b0s = f0 >> 2, q40 = f0 & 3;
      const int b1s = f1 >> 2, q41 = f1 & 3;
      float4 p0 = *(const float4*)&hm[(size_t)b0s * 512 + q40 * 4];
      float4 p1 = *(const float4*)&hm[(size_t)b1s * 512 + q41 * 4];
      for (int kc = 0; kc < 1024; kc += 16) {
        __syncthreads();
        AL[(q40 * 4 + 0) * 128 + b0s] = p0.x;
        AL[(q40 * 4 + 1) * 128 + b0s] = p0.y;
        AL[(q40 * 4 + 2) * 128 + b0s] = p0.z;
        AL[(q40 * 4 + 3) * 128 + b0s] = p0.w;
        AL[(q41 * 4 + 0) * 128 + b1s] = p1.x;
        AL[(q41 * 4 + 1) * 128 + b1s] = p1.y;
        AL[(q41 * 4 + 2) * 128 + b1s] = p1.z;
        AL[(q41 * 4 + 3) * 128 + b1s] = p1.w;
        __syncthreads();
        int kn = kc + 16;
        if (kn < 1024) {
          int k0a = kn + q40 * 4, k1a = kn + q41 * 4;
          p0 = (k0a < 512) ? *(const float4*)&hm[(size_t)b0s * 512 + k0a]
                           : *(const float4*)&ht[((size_t)b0s * THh + k) * 512 + (k0a - 512)];
          p1 = (k1a < 512) ? *(const float4*)&hm[(size_t)b1s * 512 + k1a]
                           : *(const float4*)&ht[((size_t)b1s * THh + k) * 512 + (k1a - 512)];
        }
        const int cb = half * 5;
#pragma unroll
        for (int kk = 0; kk < 16; kk += 4) {
          float a0 = AL[(kk + 0) * 128 + r];
          float a1 = AL[(kk + 1) * 128 + r];
          float a2 = AL[(kk + 2) * 128 + r];
          float a3 = AL[(kk + 3) * 128 + r];
#pragma unroll
          for (int cc = 0; cc < 5; cc++) {
            float4 bv = *(float4*)&B1[(cb + cc) * 1024 + kc + kk];
            acc1[cc] += a0 * bv.x + a1 * bv.y + a2 * bv.z + a3 * bv.w;
          }
        }
      }
      const int cbase = bid * 10 + half * 5;
#pragma unroll
      for (int cc = 0; cc < 5; cc++) {
        int c = cbase + cc;
        if (c < 512) qbuf[(size_t)r * 512 + c] = acc1[cc];
        else ghp[(size_t)r * 2048 + (c - 512)] = acc1[cc];
      }
    }
    gbar(ws, bi); bi++;
    // ---------- P2: attention (blocks 0..127, one per batch row) ----------
    if (bid < 128) {
      const int b = bid;
      const float* Wsb = ws + OFF_WSM;
      const float* hs = ws + OFF_HS;
      const float* wef = ws + OFF_WEF;
      for (int i = tid; i < 512; i += 256) {
        q_lds[i] = qbuf[(size_t)b * 512 + i];
        we_lds[i] = wef[i];
      }
      __syncthreads();
      {
        int t2 = tid >> 1;
        int gbase = (tid & 1) * 256;
        const float* wsrow = Wsb + ((size_t)b * TPp + t2) * 512 + gbase;
        float s = 0.f;
        for (int ii = 0; ii < 256; ii += 4) {
          float4 wv = *(const float4*)(wsrow + ii);
          float4 qv = *(float4*)&q_lds[gbase + ii];
          float4 ev = *(float4*)&we_lds[gbase + ii];
          s += tanh_f(wv.x + qv.x) * ev.x + tanh_f(wv.y + qv.y) * ev.y +
               tanh_f(wv.z + qv.z) * ev.z + tanh_f(wv.w + qv.w) * ev.w;
        }
        e_part[tid] = s;
      }
      __syncthreads();
      if (tid < 128) e_lds[tid] = e_part[tid * 2] + e_part[tid * 2 + 1];
      __syncthreads();
      if (tid < 64) {
        float m = fmaxf(e_lds[tid], e_lds[tid + 64]);
        for (int off = 32; off > 0; off >>= 1) m = fmaxf(m, __shfl_down(m, off));
        if (tid == 0) red_s[0] = m;
      }
      __syncthreads();
      if (tid < 128) alpha_lds[tid] = __expf(e_lds[tid] - red_s[0]);
      __syncthreads();
      if (tid < 64) {
        float s = alpha_lds[tid] + alpha_lds[tid + 64];
        for (int off = 32; off > 0; off >>= 1) s += __shfl_down(s, off);
        if (tid == 0) red_s[1] = 1.f / s;
      }
      __syncthreads();
      {
        float inv = red_s[1];
        float a0 = 0.f, a1 = 0.f;
        const float* hsb = hs + (size_t)b * TPp * 512 + tid * 2;
        for (int t2 = 0; t2 < TPp; t2++) {
          float2 hv = *(const float2*)(hsb + (size_t)t2 * 512);
          float al = alpha_lds[t2];
          a0 += al * hv.x;
          a1 += al * hv.y;
        }
        abuf[(size_t)b * 512 + tid * 2] = a0 * inv;
        abuf[(size_t)b * 512 + tid * 2 + 1] = a1 * inv;
      }
    }
    gbar(ws, bi); bi++;
    // ---------- P3: a @ WIA + ghp + bm -> cell update (block owns j-pair) ----------
    {
      float acc3[4] = {0.f, 0.f, 0.f, 0.f};
      const int f0 = tid, f1 = tid + 256;
      const int b0s = f0 >> 2, q40 = f0 & 3;
      const int b1s = f1 >> 2, q41 = f1 & 3;
      float4 p0 = *(const float4*)&abuf[(size_t)b0s * 512 + q40 * 4];
      float4 p1 = *(const float4*)&abuf[(size_t)b1s * 512 + q41 * 4];
      for (int kc = 0; kc < 512; kc += 16) {
        __syncthreads();
        AL[(q40 * 4 + 0) * 128 + b0s] = p0.x;
        AL[(q40 * 4 + 1) * 128 + b0s] = p0.y;
        AL[(q40 * 4 + 2) * 128 + b0s] = p0.z;
        AL[(q40 * 4 + 3) * 128 + b0s] = p0.w;
        AL[(q41 * 4 + 0) * 128 + b1s] = p1.x;
        AL[(q41 * 4 + 1) * 128 + b1s] = p1.y;
        AL[(q41 * 4 + 2) * 128 + b1s] = p1.z;
        AL[(q41 * 4 + 3) * 128 + b1s] = p1.w;
        __syncthreads();
        int kn = kc + 16;
        if (kn < 512) {
          p0 = *(const float4*)&abuf[(size_t)b0s * 512 + kn + q40 * 4];
          p1 = *(const float4*)&abuf[(size_t)b1s * 512 + kn + q41 * 4];
        }
#pragma unroll
        for (int kk = 0; kk < 16; kk += 4) {
          float a0 = AL[(kk + 0) * 128 + r];
          float a1 = AL[(kk + 1) * 128 + r];
          float a2 = AL[(kk + 2) * 128 + r];
          float a3 = AL[(kk + 3) * 128 + r];
#pragma unroll
          for (int g = 0; g < 4; g++) {
            float4 wv = *(float4*)&W3[(jj * 4 + g) * 512 + kc + kk];
            acc3[g] += a0 * wv.x + a1 * wv.y + a2 * wv.z + a3 * wv.w;
          }
        }
      }
      float4 gh4 = *(const float4*)&ghp[(size_t)r * 2048 + j3 * 4];
      float gi = acc3[0] + gh4.x + bmp[0];
      float gf = acc3[1] + gh4.y + bmp[1];
      float gg = acc3[2] + gh4.z + bmp[2];
      float go = acc3[3] + gh4.w + bmp[3];
      float iv = sigmf(gi), fv = sigmf(gf), gv = tanh_f(gg), ov = sigmf(go);
      float cn = fv * c_reg + iv * gv;
      float hn = ov * tanh_f(cn);
      c_reg = cn;
      hm[(size_t)r * 512 + j3] = hn;
      if (k == hl - 1) last[(size_t)r * 512 + j3] = hn;
    }
    gbar(ws, bi); bi++;
  }
}

// ---------------- FC epilogue ----------------
__global__ __launch_bounds__(256) void k_fc(const float* __restrict__ ws, const float* __restrict__ Wfc,
                                            const float* __restrict__ bfc, float* __restrict__ out) {
  int idx = blockIdx.x * 256 + threadIdx.x;
  if (idx >= BB * 3) return;
  int b = idx / 3, o = idx - b * 3;
  const float* lrow = ws + OFF_LAST + (size_t)b * 512;
  const float* wrow = Wfc + (size_t)o * 512;
  float acc = bfc[o];
  for (int h = 0; h < 512; h++) acc += lrow[h] * wrow[h];
  out[idx] = acc;
}

extern "C" void kernel_launch(void* const* d_in, const int* in_sizes, int n_in, void* d_out,
                              int out_size, void* d_ws, size_t ws_size, hipStream_t stream) {
  const int* premise = (const int*)d_in[0];
  const int* plen = (const int*)d_in[1];
  const int* hyp = (const int*)d_in[2];
  const int* hlen = (const int*)d_in[3];
  const float* emb = (const float*)d_in[4];
  const float* Wih_p = (const float*)d_in[5];
  const float* Whh_p = (const float*)d_in[6];
  const float* bih_p = (const float*)d_in[7];
  const float* bhh_p = (const float*)d_in[8];
  const float* Wih_h = (const float*)d_in[9];
  const float* Whh_h = (const float*)d_in[10];
  const float* bih_h = (const float*)d_in[11];
  const float* bhh_h = (const float*)d_in[12];
  const float* Wih_m = (const float*)d_in[13];
  const float* Whh_m = (const float*)d_in[14];
  const float* bih_m = (const float*)d_in[15];
  const float* bhh_m = (const float*)d_in[16];
  const float* w_e = (const float*)d_in[17];
  const float* W_s = (const float*)d_in[18];
  const float* W_t = (const float*)d_in[19];
  const float* W_m = (const float*)d_in[20];
  const float* W_fc = (const float*)d_in[21];
  const float* b_fc = (const float*)d_in[22];
  float* ws = (float*)d_ws;
  float* out = (float*)d_out;

  if (ws_size < WS_FLOATS * sizeof(float)) {
    float mb = (float)((double)ws_size / (1024.0 * 1024.0));
    k_diag<<<dim3(6), dim3(64), 0, stream>>>(out, mb);
    return;
  }

  // K0: weight prep + state/counter zero
  {
    size_t total = 2 * SZ_WIHT + 2 * (size_t)512 * 2048 + (size_t)2560 * 1024 +
                   (size_t)512 * 2048 + 512 + 2048 + 393216 + 131072 + 512;
    int nb = (int)((total + 255) / 256);
    k_prep<<<dim3(nb), dim3(256), 0, stream>>>(ws, Wih_p, bih_p, bhh_p, Wih_h, bih_h, bhh_h,
                                               Whh_p, Whh_h, Whh_m, Wih_m, bih_m, bhh_m,
                                               W_m, W_t, w_e);
  }
  // persistent LSTM (all 128 steps, grid-wide barriers)
  {
    void* args[] = {(void*)&ws, (void*)&premise, (void*)&hyp, (void*)&plen, (void*)&hlen, (void*)&emb};
    hipError_t e = hipLaunchCooperativeKernel((const void*)k_lstm_mega, dim3(256), dim3(256),
                                              args, 0, stream);
    if (e != hipSuccess)
      k_lstm_mega<<<dim3(256), dim3(256), 0, stream>>>(ws, premise, hyp, plen, hlen, emb);
  }
  // Ws = HS @ W_s^T (WSM region free again)
  k_gemm<<<dim3(256 * 8), dim3(256), 0, stream>>>(ws + OFF_HS, W_s, 512, 512, 512,
                                                  ws + OFF_WSM, 8);
  // persistent match loop (64 steps, 3 barriers/step)
  {
    void* args[] = {(void*)&ws, (void*)&hlen};
    hipError_t e = hipLaunchCooperativeKernel((const void*)k_match_mega, dim3(256), dim3(256),
                                              args, 0, stream);
    if (e != hipSuccess)
      k_match_mega<<<dim3(256), dim3(256), 0, stream>>>(ws, hlen);
  }
  // FC epilogue
  k_fc<<<dim3(2), dim3(256), 0, stream>>>(ws, W_fc, b_fc, out);
}

// Round 3
// 16180.717 us; speedup vs baseline: 1.2792x; 1.2792x over previous
//
#include <hip/hip_runtime.h>
#include <hip/hip_bf16.h>

// Problem constants
constexpr int BB = 128;   // batch
constexpr int TPp = 128;  // premise len
constexpr int THh = 64;   // hypothesis len
constexpr int HH = 512;   // hidden

// ---------------- workspace layout (fp32 words) ----------------
constexpr size_t OFF_HS     = 0;                               // [128][128][512]
constexpr size_t SZ_HS      = (size_t)16384 * 512;
constexpr size_t OFF_HT     = OFF_HS + SZ_HS;                  // [128][64][512]
constexpr size_t SZ_HT      = (size_t)8192 * 512;
constexpr size_t OFF_WSM    = OFF_HT + SZ_HT;                  // Ws [16384][512] (match phase)
constexpr size_t SZ_WSM     = (size_t)16384 * 512;
// During LSTM phase WSM is dead -> xg scratch (16-step chunks)
constexpr size_t OFF_XG_P   = OFF_WSM;                         // [16 tl][128 li][128 b][16 slot]
constexpr size_t OFF_XG_H   = OFF_WSM + (size_t)16 * 128 * 128 * 16;
constexpr size_t OFF_WIHT_P = OFF_WSM + SZ_WSM;                // [304][2048] (rows 300-302 zero, 303 = bih+bhh)
constexpr size_t SZ_WIHT    = (size_t)304 * 2048;
constexpr size_t OFF_WIHT_H = OFF_WIHT_P + SZ_WIHT;
constexpr size_t OFF_WHHT_P = OFF_WIHT_H + SZ_WIHT;            // WSTK_P: [128 li][512 k][16 c] c=jj*4+g
constexpr size_t OFF_WHHT_H = OFF_WHHT_P + (size_t)512 * 2048; // WSTK_H
constexpr size_t OFF_WB1T   = OFF_WHHT_H + (size_t)512 * 2048; // [2560 c][1024 k] transposed P1 weights
constexpr size_t OFF_WIA    = OFF_WB1T + (size_t)2560 * 1024;  // WIAT [2048 c][512 k], c = j*4+g
constexpr size_t OFF_WEF    = OFF_WIA + (size_t)2048 * 512;    // w_e fp32 [512]
constexpr size_t OFF_BM     = OFF_WEF + 512;                   // bih_m+bhh_m [2048]
constexpr size_t OFF_HC_P   = OFF_BM + 2048;                   // 2 x [128][512] h carry dbuf (premise)
constexpr size_t OFF_HC_H   = OFF_HC_P + 2 * (size_t)BB * HH;  // 2 x [128][512] (hyp)
constexpr size_t OFF_C_P    = OFF_HC_H + 2 * (size_t)BB * HH;  // (vestigial, kept zeroed)
constexpr size_t OFF_C_H    = OFF_C_P + (size_t)BB * HH;
constexpr size_t OFF_Q      = OFF_C_H + (size_t)BB * HH;       // [128][512]
constexpr size_t OFF_GH     = OFF_Q + (size_t)BB * HH;         // ghp [128][2048] PACKED j*4+g
constexpr size_t OFF_A      = OFF_GH + (size_t)BB * 2048;      // [128][512]
constexpr size_t OFF_HM     = OFF_A + (size_t)BB * HH;         // [128][512]
constexpr size_t OFF_CM     = OFF_HM + (size_t)BB * HH;        // (vestigial, kept zeroed)
constexpr size_t OFF_LAST   = OFF_CM + (size_t)BB * HH;        // [128][512]
// slot barriers: per-block 16-word (64B) slots + one go word, per kernel
constexpr size_t OFF_BARL   = OFF_LAST + (size_t)BB * HH;      // LSTM barrier: 256*16+16 -> pad 4352
constexpr size_t OFF_BARM   = OFF_BARL + 4352;                 // match barrier
constexpr size_t WS_FLOATS  = OFF_BARM + 4352;

__device__ __forceinline__ float sigmf(float x) { return 1.0f / (1.0f + __expf(-x)); }
__device__ __forceinline__ float tanh_f(float x) {
  float e = __expf(-2.0f * fabsf(x));
  float r = (1.0f - e) / (1.0f + e);
  return copysignf(r, x);
}

// ---- slot-based grid barrier: NO atomic RMW. Each block release-stores an epoch
// into its own 64B slot; block 0 (256 threads, 1 slot each) waits, then publishes go.
// Counters zeroed by k_prep each call (replay-safe). Grid must be exactly 256 blocks.
__device__ __forceinline__ void gbar2(unsigned* bar, int ep) {
  __syncthreads();
  const int tid = threadIdx.x;
  if (tid == 0) {
    __threadfence();
    __hip_atomic_store(bar + (size_t)blockIdx.x * 16, (unsigned)ep,
                       __ATOMIC_RELAXED, __HIP_MEMORY_SCOPE_AGENT);
  }
  if (blockIdx.x == 0) {
    while (__hip_atomic_load(bar + (size_t)tid * 16,
                             __ATOMIC_RELAXED, __HIP_MEMORY_SCOPE_AGENT) < (unsigned)ep)
      __builtin_amdgcn_s_sleep(1);
    __syncthreads();
    if (tid == 0)
      __hip_atomic_store(bar + (size_t)256 * 16, (unsigned)ep,
                         __ATOMIC_RELAXED, __HIP_MEMORY_SCOPE_AGENT);
  } else if (tid == 0) {
    while (__hip_atomic_load(bar + (size_t)256 * 16,
                             __ATOMIC_RELAXED, __HIP_MEMORY_SCOPE_AGENT) < (unsigned)ep)
      __builtin_amdgcn_s_sleep(1);
  }
  if (tid == 0) __threadfence();
  __syncthreads();
}

// ---------------- diag ----------------
__global__ void k_diag(float* out, float v) {
  int i = blockIdx.x * 64 + threadIdx.x;
  if (i < BB * 3) out[i] = v;
}

// ---------------- K0: weight transpose/stack + state/counter zero ----------------
__global__ __launch_bounds__(256) void k_prep(float* ws,
    const float* Wih_p, const float* bih_p, const float* bhh_p,
    const float* Wih_h, const float* bih_h, const float* bhh_h,
    const float* Whh_p, const float* Whh_h,
    const float* Whh_m, const float* Wih_m, const float* bih_m, const float* bhh_m,
    const float* W_m, const float* W_t, const float* w_e) {
  size_t gid = (size_t)blockIdx.x * 256 + threadIdx.x;
  if (gid < SZ_WIHT) {
    int k = (int)(gid >> 11), r = (int)(gid & 2047);
    float v = (k < 300) ? Wih_p[(size_t)r * 300 + k]
            : (k == 303) ? (bih_p[r] + bhh_p[r]) : 0.f;
    ws[OFF_WIHT_P + gid] = v;
    return;
  }
  gid -= SZ_WIHT;
  if (gid < SZ_WIHT) {
    int k = (int)(gid >> 11), r = (int)(gid & 2047);
    float v = (k < 300) ? Wih_h[(size_t)r * 300 + k]
            : (k == 303) ? (bih_h[r] + bhh_h[r]) : 0.f;
    ws[OFF_WIHT_H + gid] = v;
    return;
  }
  gid -= SZ_WIHT;
  const size_t NT = (size_t)512 * 2048;
  if (gid < NT) {  // WSTK_P [li][k][16]: c=jj*4+g -> Whh row g*512+li*4+jj, col k
    int li = (int)(gid >> 13);
    int rem = (int)(gid & 8191);
    int k = rem >> 4, c = rem & 15;
    int jj = c >> 2, g = c & 3;
    ws[OFF_WHHT_P + gid] = Whh_p[(size_t)(g * 512 + li * 4 + jj) * 512 + k];
    return;
  }
  gid -= NT;
  if (gid < NT) {  // WSTK_H
    int li = (int)(gid >> 13);
    int rem = (int)(gid & 8191);
    int k = rem >> 4, c = rem & 15;
    int jj = c >> 2, g = c & 3;
    ws[OFF_WHHT_H + gid] = Whh_h[(size_t)(g * 512 + li * 4 + jj) * 512 + k];
    return;
  }
  gid -= NT;
  if (gid < (size_t)2560 * 1024) {  // WB1T [c][k]
    int c = (int)(gid >> 10), k = (int)(gid & 1023);
    float v;
    if (c < 512) {
      v = (k < 512) ? W_m[(size_t)c * 512 + k] : W_t[(size_t)c * 512 + (k - 512)];
    } else {
      int p = c - 512;
      int j = p >> 2, g = p & 3;
      int r = g * 512 + j;
      v = (k < 512) ? Whh_m[(size_t)r * 512 + k] : Wih_m[(size_t)r * 1024 + k];
    }
    ws[OFF_WB1T + gid] = v;
    return;
  }
  gid -= (size_t)2560 * 1024;
  if (gid < (size_t)2048 * 512) {  // WIAT [c][k], c=j*4+g, k<512 (a-part of Wih_m)
    int c = (int)(gid >> 9), k = (int)(gid & 511);
    int j = c >> 2, g = c & 3;
    ws[OFF_WIA + gid] = Wih_m[((size_t)g * 512 + j) * 1024 + k];
    return;
  }
  gid -= (size_t)2048 * 512;
  if (gid < 512) { ws[OFF_WEF + gid] = w_e[gid]; return; }
  gid -= 512;
  if (gid < 2048) { ws[OFF_BM + gid] = bih_m[gid] + bhh_m[gid]; return; }
  gid -= 2048;
  if (gid < (size_t)393216) { ws[OFF_HC_P + gid] = 0.f; return; }  // HC_P,HC_H,C_P,C_H
  gid -= 393216;
  if (gid < (size_t)131072) { ws[OFF_HM + gid] = 0.f; return; }    // HM, CM
  gid -= 131072;
  if (gid < 8704) { ws[OFF_BARL + gid] = 0.f; return; }            // barrier slots (both)
}

// ---------------- generic 64x64-tile fp32 GEMM (Ws = HS @ W_s^T) ----------------
__global__ __launch_bounds__(256) void k_gemm(const float* __restrict__ A,
                                              const float* __restrict__ Bw, int ldb, int Kdim,
                                              int N, float* __restrict__ C, int ntilesN) {
  __shared__ float As[16][68];
  __shared__ float Bs[16][68];
  const int tid = threadIdx.x;
  const int bid = blockIdx.x;
  const int tm = bid / ntilesN, tn = bid % ntilesN;
  const int m0 = tm * 64, n0 = tn * 64;
  const int tx = tid & 15, ty = tid >> 4;
  const int srow = tid >> 2, skc = (tid & 3) * 4;
  float acc[4][4] = {};
  const float* arowf = A + (size_t)(m0 + srow) * Kdim;
  const float* brow = Bw + (size_t)(n0 + srow) * ldb;
  for (int k0 = 0; k0 < Kdim; k0 += 16) {
    float4 v = *(const float4*)(arowf + k0 + skc);
    As[skc + 0][srow] = v.x; As[skc + 1][srow] = v.y;
    As[skc + 2][srow] = v.z; As[skc + 3][srow] = v.w;
#pragma unroll
    for (int i = 0; i < 4; i++) Bs[skc + i][srow] = brow[k0 + skc + i];
    __syncthreads();
#pragma unroll
    for (int kk = 0; kk < 16; kk++) {
      float4 a4 = *(float4*)&As[kk][ty * 4];
      float4 b4 = *(float4*)&Bs[kk][tx * 4];
      acc[0][0] += a4.x * b4.x; acc[0][1] += a4.x * b4.y; acc[0][2] += a4.x * b4.z; acc[0][3] += a4.x * b4.w;
      acc[1][0] += a4.y * b4.x; acc[1][1] += a4.y * b4.y; acc[1][2] += a4.y * b4.z; acc[1][3] += a4.y * b4.w;
      acc[2][0] += a4.z * b4.x; acc[2][1] += a4.z * b4.y; acc[2][2] += a4.z * b4.z; acc[2][3] += a4.z * b4.w;
      acc[3][0] += a4.w * b4.x; acc[3][1] += a4.w * b4.y; acc[3][2] += a4.w * b4.z; acc[3][3] += a4.w * b4.w;
    }
    __syncthreads();
  }
  const int m = m0 + ty * 4, n = n0 + tx * 4;
#pragma unroll
  for (int i = 0; i < 4; i++) {
    float4 o = {acc[i][0], acc[i][1], acc[i][2], acc[i][3]};
    *(float4*)&C[(size_t)(m + i) * N + n] = o;
  }
}

// ---------------- persistent LSTM mega-kernel: all 128 steps + inline xg chunks ----------------
__global__ __launch_bounds__(256) void k_lstm_mega(float* __restrict__ ws,
    const int* __restrict__ premise, const int* __restrict__ hyp,
    const int* __restrict__ plen, const int* __restrict__ hlen,
    const float* __restrict__ emb) {
  __shared__ float4 smem4[4096];           // 64 KB
  float4* wlds4 = smem4;                   // [512 k][4 cg]
  float4* hbuf4 = smem4 + 2048;            // [128 b][16 k4] swizzled
  float* xAs = (float*)(smem4 + 2048);     // xg alias: [16][68]
  float* xBs = xAs + 16 * 68;
  int* xTok = (int*)(xBs + 16 * 68);

  const int tid = threadIdx.x;
  const int bid = blockIdx.x;
  const int seq = bid >> 7;
  const int li = bid & 127;
  const int T = seq ? THh : TPp;
  const int* lens = seq ? hlen : plen;
  const float* wstk = ws + (seq ? OFF_WHHT_H : OFF_WHHT_P) + (size_t)li * 8192;
  float* hsout = ws + (seq ? OFF_HT : OFF_HS);
  float* hc = ws + (seq ? OFF_HC_H : OFF_HC_P);
  unsigned* barL = (unsigned*)(ws + OFF_BARL);

  // stage Whh slice once (persists across all steps)
  {
    const float4* src = (const float4*)wstk;
#pragma unroll
    for (int j2 = 0; j2 < 8; j2++) wlds4[tid + j2 * 256] = src[tid + j2 * 256];
  }
  const int bg = tid & 63, cg = tid >> 6;
  const int b0 = 2 * bg, b1 = 2 * bg + 1;
  const int sw = bg & 7;
  const int jcol = li * 4 + cg;
  const int len0 = lens[b0], len1 = lens[b1];
  float c0r = 0.f, c1r = 0.f, h0r = 0.f, h1r = 0.f;
  int ep = 1;

  for (int t = 0; t < TPp; t++) {
    if ((t & 15) == 0) {
      // ---- inline xg chunk GEMM (tiles 64x64, K=304) ----
      int ntl = (t < THh) ? 2048 : 1024;
      __syncthreads();
      for (int tile = bid; tile < ntl; tile += 256) {
        const int seqx = tile >> 10;
        const int u = tile & 1023;
        const int tm = u >> 5, tn = u & 31;
        const int m0 = tm * 64, n0 = tn * 64;
        const int Tx = seqx ? THh : TPp;
        const int* toks = seqx ? hyp : premise;
        const float* WX = ws + (seqx ? OFF_WIHT_H : OFF_WIHT_P);
        float* xg = ws + (seqx ? OFF_XG_H : OFF_XG_P);
        if (tid < 64) {
          int r = m0 + tid;
          int tl = r >> 7, b = r & 127;
          xTok[tid] = toks[(size_t)b * Tx + t + tl];
        }
        __syncthreads();
        const int tx = tid & 15, ty = tid >> 4;
        const int sr = tid & 63, sk0 = (tid >> 6) * 4;
        const int bky = tid >> 4, bkx = (tid & 15) * 4;
        float acc[4][4] = {};
        for (int k0 = 0; k0 < 304; k0 += 16) {
          int tok = xTok[sr];
#pragma unroll
          for (int i = 0; i < 4; i++) {
            int kx = k0 + sk0 + i;
            float v = 0.f;
            if (kx < 300) v = emb[(size_t)tok * 300 + kx];
            else if (kx == 303) v = 1.0f;  // bias-one row
            xAs[(sk0 + i) * 68 + sr] = v;
          }
          *(float4*)&xBs[bky * 68 + bkx] = *(const float4*)(WX + (size_t)(k0 + bky) * 2048 + n0 + bkx);
          __syncthreads();
#pragma unroll
          for (int kk = 0; kk < 16; kk++) {
            float4 a4 = *(float4*)&xAs[kk * 68 + ty * 4];
            float4 b4 = *(float4*)&xBs[kk * 68 + tx * 4];
            acc[0][0] += a4.x * b4.x; acc[0][1] += a4.x * b4.y; acc[0][2] += a4.x * b4.z; acc[0][3] += a4.x * b4.w;
            acc[1][0] += a4.y * b4.x; acc[1][1] += a4.y * b4.y; acc[1][2] += a4.y * b4.z; acc[1][3] += a4.y * b4.w;
            acc[2][0] += a4.z * b4.x; acc[2][1] += a4.z * b4.y; acc[2][2] += a4.z * b4.z; acc[2][3] += a4.z * b4.w;
            acc[3][0] += a4.w * b4.x; acc[3][1] += a4.w * b4.y; acc[3][2] += a4.w * b4.z; acc[3][3] += a4.w * b4.w;
          }
          __syncthreads();
        }
        const int cbase = n0 + tx * 4;
        const int g = cbase >> 9;
        const int li2 = (cbase & 511) >> 2;
#pragma unroll
        for (int i = 0; i < 4; i++) {
          int r = m0 + ty * 4 + i;
          int tl = r >> 7, b = r & 127;
          float* dst = xg + (((size_t)tl * 128 + li2) * 128 + b) * 16 + g;
#pragma unroll
          for (int jj = 0; jj < 4; jj++) dst[jj * 4] = acc[i][jj];
        }
      }
      gbar2(barL, ep); ep++;
    }
    const int par = t & 1;
    const bool active = !(seq && t >= THh);
    if (active) {
      const float* hin = hc + (size_t)par * (BB * HH);
      float* hout = hc + (size_t)(par ^ 1) * (BB * HH);
      const float* xgp = ws + (seq ? OFF_XG_H : OFF_XG_P) + ((size_t)(t & 15) * 128 + li) * 2048;
      float4 acc0 = {0.f, 0.f, 0.f, 0.f}, acc1 = {0.f, 0.f, 0.f, 0.f};
      float4 pre[8];
#pragma unroll
      for (int j2 = 0; j2 < 8; j2++) {
        int fi = tid + j2 * 256, b = fi >> 4, k4 = fi & 15;
        pre[j2] = *(const float4*)(hin + (size_t)b * 512 + k4 * 4);
      }
      for (int kc = 0; kc < 512; kc += 64) {
        __syncthreads();
#pragma unroll
        for (int j2 = 0; j2 < 8; j2++) {
          int fi = tid + j2 * 256, b = fi >> 4, k4 = fi & 15;
          hbuf4[b * 16 + (k4 ^ ((b >> 1) & 7))] = pre[j2];
        }
        __syncthreads();
        if (kc + 64 < 512) {
#pragma unroll
          for (int j2 = 0; j2 < 8; j2++) {
            int fi = tid + j2 * 256, b = fi >> 4, k4 = fi & 15;
            pre[j2] = *(const float4*)(hin + (size_t)b * 512 + (kc + 64) + k4 * 4);
          }
        }
#pragma unroll
        for (int kk = 0; kk < 64; kk += 4) {
          int k4 = kk >> 2;
          float4 h0 = hbuf4[b0 * 16 + (k4 ^ sw)];
          float4 h1 = hbuf4[b1 * 16 + (k4 ^ sw)];
          float4 w0 = wlds4[(kc + kk + 0) * 4 + cg];  // wave-uniform -> broadcast
          float4 w1 = wlds4[(kc + kk + 1) * 4 + cg];
          float4 w2 = wlds4[(kc + kk + 2) * 4 + cg];
          float4 w3 = wlds4[(kc + kk + 3) * 4 + cg];
          acc0.x += h0.x * w0.x + h0.y * w1.x + h0.z * w2.x + h0.w * w3.x;
          acc0.y += h0.x * w0.y + h0.y * w1.y + h0.z * w2.y + h0.w * w3.y;
          acc0.z += h0.x * w0.z + h0.y * w1.z + h0.z * w2.z + h0.w * w3.z;
          acc0.w += h0.x * w0.w + h0.y * w1.w + h0.z * w2.w + h0.w * w3.w;
          acc1.x += h1.x * w0.x + h1.y * w1.x + h1.z * w2.x + h1.w * w3.x;
          acc1.y += h1.x * w0.y + h1.y * w1.y + h1.z * w2.y + h1.w * w3.y;
          acc1.z += h1.x * w0.z + h1.y * w1.z + h1.z * w2.z + h1.w * w3.z;
          acc1.w += h1.x * w0.w + h1.y * w1.w + h1.z * w2.w + h1.w * w3.w;
        }
      }
      float4 x0 = *(const float4*)(xgp + (size_t)b0 * 16 + cg * 4);
      float4 x1 = *(const float4*)(xgp + (size_t)b1 * 16 + cg * 4);
      {
        float iv = sigmf(acc0.x + x0.x), fv = sigmf(acc0.y + x0.y);
        float gv = tanh_f(acc0.z + x0.z), ov = sigmf(acc0.w + x0.w);
        float cn = fv * c0r + iv * gv;
        float hn = ov * tanh_f(cn);
        bool inr = t < len0;
        if (inr) { c0r = cn; h0r = hn; }
        hsout[((size_t)b0 * T + t) * 512 + jcol] = inr ? hn : 0.f;
        hout[(size_t)b0 * 512 + jcol] = h0r;
      }
      {
        float iv = sigmf(acc1.x + x1.x), fv = sigmf(acc1.y + x1.y);
        float gv = tanh_f(acc1.z + x1.z), ov = sigmf(acc1.w + x1.w);
        float cn = fv * c1r + iv * gv;
        float hn = ov * tanh_f(cn);
        bool inr = t < len1;
        if (inr) { c1r = cn; h1r = hn; }
        hsout[((size_t)b1 * T + t) * 512 + jcol] = inr ? hn : 0.f;
        hout[(size_t)b1 * 512 + jcol] = h1r;
      }
    }
    gbar2(barL, ep); ep++;
  }
}

// ---------------- persistent match mega-kernel: 64 steps x {P1,P2,P3} ----------------
// LDS: B1 [10 c][1024 k] 40KB | W3 [8 c][512 k] 16KB | AL4 [4 k4][128 b] float4 8KB = 64KB
// half = tid>>7 (per-WAVE) -> all B reads are wave-uniform LDS broadcasts.
// A staged k-major float4 -> conflict-free b128 store/load.
__global__ __launch_bounds__(256) void k_match_mega(float* __restrict__ ws,
                                                    const int* __restrict__ hlen) {
  __shared__ float smem[16384];  // 64 KB exactly
  float* B1 = smem;              // [10][1024]
  float* W3 = smem + 10240;      // [8][512]
  float4* AL4 = (float4*)(smem + 14336);  // [4][128] float4
  float* P2b = smem + 14336;     // P2 aliases (2048 floats)
  float* q_lds = P2b; float* we_lds = P2b + 512; float* e_part = P2b + 1024;
  float* e_lds = P2b + 1280; float* alpha_lds = P2b + 1408; float* red_s = P2b + 1536;

  const int tid = threadIdx.x;
  const int bid = blockIdx.x;
  float* hm = ws + OFF_HM;
  const float* ht = ws + OFF_HT;
  float* qbuf = ws + OFF_Q;
  float* ghp = ws + OFF_GH;
  float* abuf = ws + OFF_A;
  float* last = ws + OFF_LAST;
  unsigned* barM = (unsigned*)(ws + OFF_BARM);

  // stage persistent weight slices (coalesced)
  {
    const float* wb1t = ws + OFF_WB1T + (size_t)bid * 10 * 1024;
    for (int i = tid; i < 10 * 1024; i += 256) B1[i] = wb1t[i];
    const float* wiat = ws + OFF_WIA + (size_t)bid * 8 * 512;
    for (int i = tid; i < 8 * 512; i += 256) W3[i] = wiat[i];
  }
  const int half = tid >> 7;            // per-wave-pair: waves 0-1 -> 0, waves 2-3 -> 1
  const int r = tid & 127;              // batch row owned by this thread
  const int j3 = bid * 2 + half;        // P3 hidden col owned by this thread
  const int b0s = tid >> 2, q40 = tid & 3;        // staging: f0 = tid
  const int b1s = 64 + (tid >> 2), q41 = tid & 3; // staging: f1 = tid + 256
  float c_reg = 0.f;
  float bmp[4];
#pragma unroll
  for (int g = 0; g < 4; g++) bmp[g] = ws[OFF_BM + g * 512 + j3];
  const int hl = hlen[r];
  int ep = 1;
  __syncthreads();

  for (int k = 0; k < THh; k++) {
    // ---------- P1: q + ghp = [hm | htk] @ WB1T (block owns 10 cols) ----------
    {
      float acc1[5] = {0.f, 0.f, 0.f, 0.f, 0.f};
      float4 p0 = *(const float4*)&hm[(size_t)b0s * 512 + q40 * 4];
      float4 p1 = *(const float4*)&hm[(size_t)b1s * 512 + q41 * 4];
      for (int kc = 0; kc < 1024; kc += 16) {
        __syncthreads();
        AL4[q40 * 128 + b0s] = p0;
        AL4[q41 * 128 + b1s] = p1;
        __syncthreads();
        int kn = kc + 16;
        if (kn < 1024) {
          int k0a = kn + q40 * 4, k1a = kn + q41 * 4;
          p0 = (k0a < 512) ? *(const float4*)&hm[(size_t)b0s * 512 + k0a]
                           : *(const float4*)&ht[((size_t)b0s * THh + k) * 512 + (k0a - 512)];
          p1 = (k1a < 512) ? *(const float4*)&hm[(size_t)b1s * 512 + k1a]
                           : *(const float4*)&ht[((size_t)b1s * THh + k) * 512 + (k1a - 512)];
        }
        const int cb = half * 5;
#pragma unroll
        for (int kk = 0; kk < 16; kk += 4) {
          float4 av = AL4[(kk >> 2) * 128 + r];
#pragma unroll
          for (int cc = 0; cc < 5; cc++) {
            float4 bv = *(float4*)&B1[(cb + cc) * 1024 + kc + kk];  // wave-uniform
            acc1[cc] += av.x * bv.x + av.y * bv.y + av.z * bv.z + av.w * bv.w;
          }
        }
      }
      const int cbase = bid * 10 + half * 5;
#pragma unroll
      for (int cc = 0; cc < 5; cc++) {
        int c = cbase + cc;
        if (c < 512) qbuf[(size_t)r * 512 + c] = acc1[cc];
        else ghp[(size_t)r * 2048 + (c - 512)] = acc1[cc];
      }
    }
    gbar2(barM, ep); ep++;
    // ---------- P2: attention (blocks 0..127, one per batch row) ----------
    if (bid < 128) {
      const int b = bid;
      const float* Wsb = ws + OFF_WSM;
      const float* hs = ws + OFF_HS;
      const float* wef = ws + OFF_WEF;
      for (int i = tid; i < 512; i += 256) {
        q_lds[i] = qbuf[(size_t)b * 512 + i];
        we_lds[i] = wef[i];
      }
      __syncthreads();
      {
        int t2 = tid >> 1;
        int gbase = (tid & 1) * 256;
        const float* wsrow = Wsb + ((size_t)b * TPp + t2) * 512 + gbase;
        float s = 0.f;
        for (int ii = 0; ii < 256; ii += 4) {
          float4 wv = *(const float4*)(wsrow + ii);
          float4 qv = *(float4*)&q_lds[gbase + ii];
          float4 ev = *(float4*)&we_lds[gbase + ii];
          s += tanh_f(wv.x + qv.x) * ev.x + tanh_f(wv.y + qv.y) * ev.y +
               tanh_f(wv.z + qv.z) * ev.z + tanh_f(wv.w + qv.w) * ev.w;
        }
        e_part[tid] = s;
      }
      __syncthreads();
      if (tid < 128) e_lds[tid] = e_part[tid * 2] + e_part[tid * 2 + 1];
      __syncthreads();
      if (tid < 64) {
        float m = fmaxf(e_lds[tid], e_lds[tid + 64]);
        for (int off = 32; off > 0; off >>= 1) m = fmaxf(m, __shfl_down(m, off));
        if (tid == 0) red_s[0] = m;
      }
      __syncthreads();
      if (tid < 128) alpha_lds[tid] = __expf(e_lds[tid] - red_s[0]);
      __syncthreads();
      if (tid < 64) {
        float s = alpha_lds[tid] + alpha_lds[tid + 64];
        for (int off = 32; off > 0; off >>= 1) s += __shfl_down(s, off);
        if (tid == 0) red_s[1] = 1.f / s;
      }
      __syncthreads();
      {
        float inv = red_s[1];
        float a0 = 0.f, a1 = 0.f;
        const float* hsb = hs + (size_t)b * TPp * 512 + tid * 2;
        for (int t2 = 0; t2 < TPp; t2++) {
          float2 hv = *(const float2*)(hsb + (size_t)t2 * 512);
          float al = alpha_lds[t2];
          a0 += al * hv.x;
          a1 += al * hv.y;
        }
        abuf[(size_t)b * 512 + tid * 2] = a0 * inv;
        abuf[(size_t)b * 512 + tid * 2 + 1] = a1 * inv;
      }
    }
    gbar2(barM, ep); ep++;
    // ---------- P3: a @ WIAT + ghp + bm -> cell update (thread owns (r, j3)) ----------
    {
      float acc3[4] = {0.f, 0.f, 0.f, 0.f};
      float4 p0 = *(const float4*)&abuf[(size_t)b0s * 512 + q40 * 4];
      float4 p1 = *(const float4*)&abuf[(size_t)b1s * 512 + q41 * 4];
      for (int kc = 0; kc < 512; kc += 16) {
        __syncthreads();
        AL4[q40 * 128 + b0s] = p0;
        AL4[q41 * 128 + b1s] = p1;
        __syncthreads();
        int kn = kc + 16;
        if (kn < 512) {
          p0 = *(const float4*)&abuf[(size_t)b0s * 512 + kn + q40 * 4];
          p1 = *(const float4*)&abuf[(size_t)b1s * 512 + kn + q41 * 4];
        }
#pragma unroll
        for (int kk = 0; kk < 16; kk += 4) {
          float4 av = AL4[(kk >> 2) * 128 + r];
#pragma unroll
          for (int g = 0; g < 4; g++) {
            float4 wv = *(float4*)&W3[(half * 4 + g) * 512 + kc + kk];  // wave-uniform
            acc3[g] += av.x * wv.x + av.y * wv.y + av.z * wv.z + av.w * wv.w;
          }
        }
      }
      float4 gh4 = *(const float4*)&ghp[(size_t)r * 2048 + j3 * 4];
      float gi = acc3[0] + gh4.x + bmp[0];
      float gf = acc3[1] + gh4.y + bmp[1];
      float gg = acc3[2] + gh4.z + bmp[2];
      float go = acc3[3] + gh4.w + bmp[3];
      float iv = sigmf(gi), fv = sigmf(gf), gv = tanh_f(gg), ov = sigmf(go);
      float cn = fv * c_reg + iv * gv;
      float hn = ov * tanh_f(cn);
      c_reg = cn;
      hm[(size_t)r * 512 + j3] = hn;
      if (k == hl - 1) last[(size_t)r * 512 + j3] = hn;
    }
    gbar2(barM, ep); ep++;
  }
}

// ---------------- FC epilogue ----------------
__global__ __launch_bounds__(256) void k_fc(const float* __restrict__ ws, const float* __restrict__ Wfc,
                                            const float* __restrict__ bfc, float* __restrict__ out) {
  int idx = blockIdx.x * 256 + threadIdx.x;
  if (idx >= BB * 3) return;
  int b = idx / 3, o = idx - b * 3;
  const float* lrow = ws + OFF_LAST + (size_t)b * 512;
  const float* wrow = Wfc + (size_t)o * 512;
  float acc = bfc[o];
  for (int h = 0; h < 512; h++) acc += lrow[h] * wrow[h];
  out[idx] = acc;
}

extern "C" void kernel_launch(void* const* d_in, const int* in_sizes, int n_in, void* d_out,
                              int out_size, void* d_ws, size_t ws_size, hipStream_t stream) {
  const int* premise = (const int*)d_in[0];
  const int* plen = (const int*)d_in[1];
  const int* hyp = (const int*)d_in[2];
  const int* hlen = (const int*)d_in[3];
  const float* emb = (const float*)d_in[4];
  const float* Wih_p = (const float*)d_in[5];
  const float* Whh_p = (const float*)d_in[6];
  const float* bih_p = (const float*)d_in[7];
  const float* bhh_p = (const float*)d_in[8];
  const float* Wih_h = (const float*)d_in[9];
  const float* Whh_h = (const float*)d_in[10];
  const float* bih_h = (const float*)d_in[11];
  const float* bhh_h = (const float*)d_in[12];
  const float* Wih_m = (const float*)d_in[13];
  const float* Whh_m = (const float*)d_in[14];
  const float* bih_m = (const float*)d_in[15];
  const float* bhh_m = (const float*)d_in[16];
  const float* w_e = (const float*)d_in[17];
  const float* W_s = (const float*)d_in[18];
  const float* W_t = (const float*)d_in[19];
  const float* W_m = (const float*)d_in[20];
  const float* W_fc = (const float*)d_in[21];
  const float* b_fc = (const float*)d_in[22];
  float* ws = (float*)d_ws;
  float* out = (float*)d_out;

  if (ws_size < WS_FLOATS * sizeof(float)) {
    float mb = (float)((double)ws_size / (1024.0 * 1024.0));
    k_diag<<<dim3(6), dim3(64), 0, stream>>>(out, mb);
    return;
  }

  // K0: weight prep + state/counter zero
  {
    size_t total = 2 * SZ_WIHT + 2 * (size_t)512 * 2048 + (size_t)2560 * 1024 +
                   (size_t)2048 * 512 + 512 + 2048 + 393216 + 131072 + 8704;
    int nb = (int)((total + 255) / 256);
    k_prep<<<dim3(nb), dim3(256), 0, stream>>>(ws, Wih_p, bih_p, bhh_p, Wih_h, bih_h, bhh_h,
                                               Whh_p, Whh_h, Whh_m, Wih_m, bih_m, bhh_m,
                                               W_m, W_t, w_e);
  }
  // persistent LSTM (all 128 steps, slot-barrier grid sync)
  {
    void* args[] = {(void*)&ws, (void*)&premise, (void*)&hyp, (void*)&plen, (void*)&hlen, (void*)&emb};
    hipError_t e = hipLaunchCooperativeKernel((const void*)k_lstm_mega, dim3(256), dim3(256),
                                              args, 0, stream);
    if (e != hipSuccess)
      k_lstm_mega<<<dim3(256), dim3(256), 0, stream>>>(ws, premise, hyp, plen, hlen, emb);
  }
  // Ws = HS @ W_s^T (WSM region free again)
  k_gemm<<<dim3(256 * 8), dim3(256), 0, stream>>>(ws + OFF_HS, W_s, 512, 512, 512,
                                                  ws + OFF_WSM, 8);
  // persistent match loop (64 steps, 3 slot-barriers/step)
  {
    void* args[] = {(void*)&ws, (void*)&hlen};
    hipError_t e = hipLaunchCooperativeKernel((const void*)k_match_mega, dim3(256), dim3(256),
                                              args, 0, stream);
    if (e != hipSuccess)
      k_match_mega<<<dim3(256), dim3(256), 0, stream>>>(ws, hlen);
  }
  // FC epilogue
  k_fc<<<dim3(2), dim3(256), 0, stream>>>(ws, W_fc, b_fc, out);
}

// Round 4
// 13871.976 us; speedup vs baseline: 1.4921x; 1.1664x over previous
//
#include <hip/hip_runtime.h>
#include <hip/hip_bf16.h>

// Problem constants
constexpr int BB = 128;   // batch
constexpr int TPp = 128;  // premise len
constexpr int THh = 64;   // hypothesis len
constexpr int HH = 512;   // hidden

// ---------------- workspace layout (fp32 words) ----------------
constexpr size_t OFF_HS     = 0;                               // [128][128][512]
constexpr size_t SZ_HS      = (size_t)16384 * 512;
constexpr size_t OFF_HT     = OFF_HS + SZ_HS;                  // [128][64][512]
constexpr size_t SZ_HT      = (size_t)8192 * 512;
constexpr size_t OFF_WSM    = OFF_HT + SZ_HT;                  // Ws [16384][512] (match phase)
constexpr size_t SZ_WSM     = (size_t)16384 * 512;
// During LSTM phase WSM is dead -> xg scratch (16-step chunks)
constexpr size_t OFF_XG_P   = OFF_WSM;                         // [16 tl][128 li][128 b][16 slot]
constexpr size_t OFF_XG_H   = OFF_WSM + (size_t)16 * 128 * 128 * 16;
constexpr size_t OFF_WIHT_P = OFF_WSM + SZ_WSM;                // [304][2048] (rows 300-302 zero, 303 = bih+bhh)
constexpr size_t SZ_WIHT    = (size_t)304 * 2048;
constexpr size_t OFF_WIHT_H = OFF_WIHT_P + SZ_WIHT;
constexpr size_t OFF_WHHT_P = OFF_WIHT_H + SZ_WIHT;            // WSTK_P: [128 li][512 k][16 c] c=jj*4+g
constexpr size_t OFF_WHHT_H = OFF_WHHT_P + (size_t)512 * 2048; // WSTK_H
constexpr size_t OFF_WB1T   = OFF_WHHT_H + (size_t)512 * 2048; // [2560 c][1024 k] transposed P1 weights
constexpr size_t OFF_WIA    = OFF_WB1T + (size_t)2560 * 1024;  // WIAT [2048 c][512 k], c = j*4+g
constexpr size_t OFF_WEF    = OFF_WIA + (size_t)2048 * 512;    // w_e fp32 [512]
constexpr size_t OFF_BM     = OFF_WEF + 512;                   // bih_m+bhh_m [2048]
constexpr size_t OFF_HC_P   = OFF_BM + 2048;                   // 2 x [128][512] h carry dbuf (premise)
constexpr size_t OFF_HC_H   = OFF_HC_P + 2 * (size_t)BB * HH;  // 2 x [128][512] (hyp)
constexpr size_t OFF_C_P    = OFF_HC_H + 2 * (size_t)BB * HH;  // (vestigial, kept zeroed)
constexpr size_t OFF_C_H    = OFF_C_P + (size_t)BB * HH;
constexpr size_t OFF_Q      = OFF_C_H + (size_t)BB * HH;       // qT [512 c][128 b]
constexpr size_t OFF_GH     = OFF_Q + (size_t)BB * HH;         // ghT [2048 c][128 b] PACKED c=j*4+g
constexpr size_t OFF_A      = OFF_GH + (size_t)BB * 2048;      // [128][512]
constexpr size_t OFF_HM     = OFF_A + (size_t)BB * HH;         // [128][512]
constexpr size_t OFF_CM     = OFF_HM + (size_t)BB * HH;        // (vestigial, kept zeroed)
constexpr size_t OFF_LAST   = OFF_CM + (size_t)BB * HH;        // [128][512]
// slot barriers: per-block 16-word (64B) slots + go word
constexpr size_t OFF_BARP   = OFF_LAST + (size_t)BB * HH;      // premise step barrier (129*16 -> 2560)
constexpr size_t OFF_BARH   = OFF_BARP + 2560;                 // hyp step barrier
constexpr size_t OFF_BARF   = OFF_BARH + 2560;                 // full barrier (257*16 -> 4352)
constexpr size_t OFF_BARM   = OFF_BARF + 4352;                 // match barrier
constexpr size_t WS_FLOATS  = OFF_BARM + 4352;

__device__ __forceinline__ float sigmf(float x) { return 1.0f / (1.0f + __expf(-x)); }
__device__ __forceinline__ float tanh_f(float x) {
  float e = __expf(-2.0f * fabsf(x));
  float r = (1.0f - e) / (1.0f + e);
  return copysignf(r, x);
}

// ---- slot-based grid barrier over blocks [base, base+n): no atomic RMW.
// Each block release-stores an epoch into its own 64B slot; leader (rel==0)
// polls all n slots (one per thread), then publishes go at slot n.
__device__ __forceinline__ void gbarN(unsigned* bar, int ep, int base, int n) {
  __syncthreads();
  const int tid = threadIdx.x;
  const int rel = (int)blockIdx.x - base;
  if (tid == 0) {
    __threadfence();
    __hip_atomic_store(bar + (size_t)rel * 16, (unsigned)ep,
                       __ATOMIC_RELAXED, __HIP_MEMORY_SCOPE_AGENT);
  }
  if (rel == 0) {
    for (int s = tid; s < n; s += (int)blockDim.x) {
      while (__hip_atomic_load(bar + (size_t)s * 16,
                               __ATOMIC_RELAXED, __HIP_MEMORY_SCOPE_AGENT) < (unsigned)ep)
        __builtin_amdgcn_s_sleep(1);
    }
    __syncthreads();
    if (tid == 0)
      __hip_atomic_store(bar + (size_t)n * 16, (unsigned)ep,
                         __ATOMIC_RELAXED, __HIP_MEMORY_SCOPE_AGENT);
  } else if (tid == 0) {
    while (__hip_atomic_load(bar + (size_t)n * 16,
                             __ATOMIC_RELAXED, __HIP_MEMORY_SCOPE_AGENT) < (unsigned)ep)
      __builtin_amdgcn_s_sleep(1);
  }
  if (tid == 0) __threadfence();
  __syncthreads();
}

// ---------------- diag ----------------
__global__ void k_diag(float* out, float v) {
  int i = blockIdx.x * 64 + threadIdx.x;
  if (i < BB * 3) out[i] = v;
}

// ---------------- K0: weight transpose/stack + state/counter zero ----------------
__global__ __launch_bounds__(256) void k_prep(float* ws,
    const float* Wih_p, const float* bih_p, const float* bhh_p,
    const float* Wih_h, const float* bih_h, const float* bhh_h,
    const float* Whh_p, const float* Whh_h,
    const float* Whh_m, const float* Wih_m, const float* bih_m, const float* bhh_m,
    const float* W_m, const float* W_t, const float* w_e) {
  size_t gid = (size_t)blockIdx.x * 256 + threadIdx.x;
  if (gid < SZ_WIHT) {
    int k = (int)(gid >> 11), r = (int)(gid & 2047);
    float v = (k < 300) ? Wih_p[(size_t)r * 300 + k]
            : (k == 303) ? (bih_p[r] + bhh_p[r]) : 0.f;
    ws[OFF_WIHT_P + gid] = v;
    return;
  }
  gid -= SZ_WIHT;
  if (gid < SZ_WIHT) {
    int k = (int)(gid >> 11), r = (int)(gid & 2047);
    float v = (k < 300) ? Wih_h[(size_t)r * 300 + k]
            : (k == 303) ? (bih_h[r] + bhh_h[r]) : 0.f;
    ws[OFF_WIHT_H + gid] = v;
    return;
  }
  gid -= SZ_WIHT;
  const size_t NT = (size_t)512 * 2048;
  if (gid < NT) {  // WSTK_P [li][k][16]: c=jj*4+g -> Whh row g*512+li*4+jj, col k
    int li = (int)(gid >> 13);
    int rem = (int)(gid & 8191);
    int k = rem >> 4, c = rem & 15;
    int jj = c >> 2, g = c & 3;
    ws[OFF_WHHT_P + gid] = Whh_p[(size_t)(g * 512 + li * 4 + jj) * 512 + k];
    return;
  }
  gid -= NT;
  if (gid < NT) {  // WSTK_H
    int li = (int)(gid >> 13);
    int rem = (int)(gid & 8191);
    int k = rem >> 4, c = rem & 15;
    int jj = c >> 2, g = c & 3;
    ws[OFF_WHHT_H + gid] = Whh_h[(size_t)(g * 512 + li * 4 + jj) * 512 + k];
    return;
  }
  gid -= NT;
  if (gid < (size_t)2560 * 1024) {  // WB1T [c][k]
    int c = (int)(gid >> 10), k = (int)(gid & 1023);
    float v;
    if (c < 512) {
      v = (k < 512) ? W_m[(size_t)c * 512 + k] : W_t[(size_t)c * 512 + (k - 512)];
    } else {
      int p = c - 512;
      int j = p >> 2, g = p & 3;
      int r = g * 512 + j;
      v = (k < 512) ? Whh_m[(size_t)r * 512 + k] : Wih_m[(size_t)r * 1024 + k];
    }
    ws[OFF_WB1T + gid] = v;
    return;
  }
  gid -= (size_t)2560 * 1024;
  if (gid < (size_t)2048 * 512) {  // WIAT [c][k], c=j*4+g (a-part of Wih_m)
    int c = (int)(gid >> 9), k = (int)(gid & 511);
    int j = c >> 2, g = c & 3;
    ws[OFF_WIA + gid] = Wih_m[((size_t)g * 512 + j) * 1024 + k];
    return;
  }
  gid -= (size_t)2048 * 512;
  if (gid < 512) { ws[OFF_WEF + gid] = w_e[gid]; return; }
  gid -= 512;
  if (gid < 2048) { ws[OFF_BM + gid] = bih_m[gid] + bhh_m[gid]; return; }
  gid -= 2048;
  if (gid < (size_t)393216) { ws[OFF_HC_P + gid] = 0.f; return; }  // HC_P,HC_H,C_P,C_H
  gid -= 393216;
  if (gid < (size_t)131072) { ws[OFF_HM + gid] = 0.f; return; }    // HM, CM
  gid -= 131072;
  if (gid < 11824) { ws[OFF_BARP + gid] = 0.f; return; }           // all barrier slots
}

// ---------------- generic 64x64-tile fp32 GEMM (Ws = HS @ W_s^T) ----------------
__global__ __launch_bounds__(256) void k_gemm(const float* __restrict__ A,
                                              const float* __restrict__ Bw, int ldb, int Kdim,
                                              int N, float* __restrict__ C, int ntilesN) {
  __shared__ float As[16][68];
  __shared__ float Bs[16][68];
  const int tid = threadIdx.x;
  const int bid = blockIdx.x;
  const int tm = bid / ntilesN, tn = bid % ntilesN;
  const int m0 = tm * 64, n0 = tn * 64;
  const int tx = tid & 15, ty = tid >> 4;
  const int srow = tid >> 2, skc = (tid & 3) * 4;
  float acc[4][4] = {};
  const float* arowf = A + (size_t)(m0 + srow) * Kdim;
  const float* brow = Bw + (size_t)(n0 + srow) * ldb;
  for (int k0 = 0; k0 < Kdim; k0 += 16) {
    float4 v = *(const float4*)(arowf + k0 + skc);
    As[skc + 0][srow] = v.x; As[skc + 1][srow] = v.y;
    As[skc + 2][srow] = v.z; As[skc + 3][srow] = v.w;
#pragma unroll
    for (int i = 0; i < 4; i++) Bs[skc + i][srow] = brow[k0 + skc + i];
    __syncthreads();
#pragma unroll
    for (int kk = 0; kk < 16; kk++) {
      float4 a4 = *(float4*)&As[kk][ty * 4];
      float4 b4 = *(float4*)&Bs[kk][tx * 4];
      acc[0][0] += a4.x * b4.x; acc[0][1] += a4.x * b4.y; acc[0][2] += a4.x * b4.z; acc[0][3] += a4.x * b4.w;
      acc[1][0] += a4.y * b4.x; acc[1][1] += a4.y * b4.y; acc[1][2] += a4.y * b4.z; acc[1][3] += a4.y * b4.w;
      acc[2][0] += a4.z * b4.x; acc[2][1] += a4.z * b4.y; acc[2][2] += a4.z * b4.z; acc[2][3] += a4.z * b4.w;
      acc[3][0] += a4.w * b4.x; acc[3][1] += a4.w * b4.y; acc[3][2] += a4.w * b4.z; acc[3][3] += a4.w * b4.w;
    }
    __syncthreads();
  }
  const int m = m0 + ty * 4, n = n0 + tx * 4;
#pragma unroll
  for (int i = 0; i < 4; i++) {
    float4 o = {acc[i][0], acc[i][1], acc[i][2], acc[i][3]};
    *(float4*)&C[(size_t)(m + i) * N + n] = o;
  }
}

// ---------------- persistent LSTM mega-kernel: 512 threads, all 128 steps ----------------
__global__ __launch_bounds__(512, 2) void k_lstm_mega(float* __restrict__ ws,
    const int* __restrict__ premise, const int* __restrict__ hyp,
    const int* __restrict__ plen, const int* __restrict__ hlen,
    const float* __restrict__ emb) {
  __shared__ float4 smem4[4096];           // 64 KB
  float4* wlds4 = smem4;                   // [512 k][4 cg]
  float4* hbuf4 = smem4 + 2048;            // [128 b][16 k4] swizzled
  float* xAs = (float*)(smem4 + 2048);     // xg alias: [16][68]
  float* xBs = xAs + 16 * 68;
  int* xTok = (int*)(xBs + 16 * 68);

  const int tid = threadIdx.x;
  const int bid = blockIdx.x;
  const int seq = bid >> 7;
  const int li = bid & 127;
  const int T = seq ? THh : TPp;
  const int* lens = seq ? hlen : plen;
  const float* wstk = ws + (seq ? OFF_WHHT_H : OFF_WHHT_P) + (size_t)li * 8192;
  float* hsout = ws + (seq ? OFF_HT : OFF_HS);
  float* hc = ws + (seq ? OFF_HC_H : OFF_HC_P);
  unsigned* barS = (unsigned*)(ws + (seq ? OFF_BARH : OFF_BARP));
  unsigned* barF = (unsigned*)(ws + OFF_BARF);
  const int sbase = seq ? 128 : 0;

  // stage Whh slice once (persists across all steps)
  {
    const float4* src = (const float4*)wstk;
#pragma unroll
    for (int j2 = 0; j2 < 4; j2++) wlds4[tid + j2 * 512] = src[tid + j2 * 512];
  }
  const int w = tid >> 6, lane = tid & 63;
  const int cg = w & 3, bh = w >> 2;
  const int b = bh * 64 + lane;
  const int sw = b & 7;
  const int jcol = li * 4 + cg;
  const int len = lens[b];
  float c_r = 0.f, h_r = 0.f;
  int epS = 1, epF = 1;

  int sb[4], sk[4];
#pragma unroll
  for (int j2 = 0; j2 < 4; j2++) { int fi = tid + j2 * 512; sb[j2] = fi >> 4; sk[j2] = fi & 15; }

  for (int t = 0; t < TPp; t++) {
    if ((t & 15) == 0) {
      if (t > 0) { gbarN(barF, epF, 0, 256); epF++; }  // all steps of prev window done
      // ---- inline xg chunk GEMM (tiles 64x64, K=304), 512 threads ----
      int ntl = (t < THh) ? 2048 : 1024;
      __syncthreads();
      for (int tile = bid; tile < ntl; tile += 256) {
        const int seqx = tile >> 10;
        const int u = tile & 1023;
        const int tm = u >> 5, tn = u & 31;
        const int m0 = tm * 64, n0 = tn * 64;
        const int Tx = seqx ? THh : TPp;
        const int* toks = seqx ? hyp : premise;
        const float* WX = ws + (seqx ? OFF_WIHT_H : OFF_WIHT_P);
        float* xg = ws + (seqx ? OFF_XG_H : OFF_XG_P);
        if (tid < 64) {
          int rr = m0 + tid;
          int tl = rr >> 7, bb = rr & 127;
          xTok[tid] = toks[(size_t)bb * Tx + t + tl];
        }
        __syncthreads();
        const int sr = tid & 63;
        const int sk2 = (tid >> 6) * 2;
        const int tx = tid & 15, ty = tid >> 4;  // ty 0..31
        float acc2[2][4] = {};
        for (int k0 = 0; k0 < 304; k0 += 16) {
          int tok = xTok[sr];
#pragma unroll
          for (int i = 0; i < 2; i++) {
            int kx = k0 + sk2 + i;
            float v = 0.f;
            if (kx < 300) v = emb[(size_t)tok * 300 + kx];
            else if (kx == 303) v = 1.0f;  // bias-one row
            xAs[(sk2 + i) * 68 + sr] = v;
          }
#pragma unroll
          for (int s = 0; s < 2; s++) {
            int i2 = tid + s * 512;
            int kb = i2 >> 6, nb = i2 & 63;
            xBs[kb * 68 + nb] = WX[(size_t)(k0 + kb) * 2048 + n0 + nb];
          }
          __syncthreads();
#pragma unroll
          for (int kk = 0; kk < 16; kk++) {
            float a0 = xAs[kk * 68 + ty * 2];
            float a1 = xAs[kk * 68 + ty * 2 + 1];
            float4 b4 = *(float4*)&xBs[kk * 68 + tx * 4];
            acc2[0][0] += a0 * b4.x; acc2[0][1] += a0 * b4.y; acc2[0][2] += a0 * b4.z; acc2[0][3] += a0 * b4.w;
            acc2[1][0] += a1 * b4.x; acc2[1][1] += a1 * b4.y; acc2[1][2] += a1 * b4.z; acc2[1][3] += a1 * b4.w;
          }
          __syncthreads();
        }
        const int cbase = n0 + tx * 4;
        const int g = cbase >> 9;
        const int li2 = (cbase & 511) >> 2;
#pragma unroll
        for (int i = 0; i < 2; i++) {
          int rr = m0 + ty * 2 + i;
          int tl = rr >> 7, brow = rr & 127;
          float* dst = xg + (((size_t)tl * 128 + li2) * 128 + brow) * 16 + g;
#pragma unroll
          for (int jj = 0; jj < 4; jj++) dst[jj * 4] = acc2[i][jj];
        }
      }
      gbarN(barF, epF, 0, 256); epF++;  // xg ready
    }
    if (!(seq && t >= THh)) {
      const int par = t & 1;
      const float* hin = hc + (size_t)par * (BB * HH);
      float* hout = hc + (size_t)(par ^ 1) * (BB * HH);
      const float* xgp = ws + (seq ? OFF_XG_H : OFF_XG_P) + ((size_t)(t & 15) * 128 + li) * 2048;
      float4 acc = {0.f, 0.f, 0.f, 0.f};
      float4 pre[4];
#pragma unroll
      for (int j2 = 0; j2 < 4; j2++)
        pre[j2] = *(const float4*)(hin + (size_t)sb[j2] * 512 + sk[j2] * 4);
      for (int kc = 0; kc < 512; kc += 64) {
        __syncthreads();
#pragma unroll
        for (int j2 = 0; j2 < 4; j2++)
          hbuf4[sb[j2] * 16 + (sk[j2] ^ (sb[j2] & 7))] = pre[j2];
        __syncthreads();
        if (kc + 64 < 512) {
#pragma unroll
          for (int j2 = 0; j2 < 4; j2++)
            pre[j2] = *(const float4*)(hin + (size_t)sb[j2] * 512 + (kc + 64) + sk[j2] * 4);
        }
#pragma unroll
        for (int kk = 0; kk < 64; kk += 4) {
          int k4 = kk >> 2;
          float4 h4 = hbuf4[b * 16 + (k4 ^ sw)];
          float4 w0 = wlds4[(kc + kk + 0) * 4 + cg];  // wave-uniform -> broadcast
          float4 w1 = wlds4[(kc + kk + 1) * 4 + cg];
          float4 w2 = wlds4[(kc + kk + 2) * 4 + cg];
          float4 w3 = wlds4[(kc + kk + 3) * 4 + cg];
          acc.x += h4.x * w0.x + h4.y * w1.x + h4.z * w2.x + h4.w * w3.x;
          acc.y += h4.x * w0.y + h4.y * w1.y + h4.z * w2.y + h4.w * w3.y;
          acc.z += h4.x * w0.z + h4.y * w1.z + h4.z * w2.z + h4.w * w3.z;
          acc.w += h4.x * w0.w + h4.y * w1.w + h4.z * w2.w + h4.w * w3.w;
        }
      }
      float4 x0 = *(const float4*)(xgp + (size_t)b * 16 + cg * 4);
      float iv = sigmf(acc.x + x0.x), fv = sigmf(acc.y + x0.y);
      float gv = tanh_f(acc.z + x0.z), ov = sigmf(acc.w + x0.w);
      float cn = fv * c_r + iv * gv;
      float hn = ov * tanh_f(cn);
      bool inr = t < len;
      if (inr) { c_r = cn; h_r = hn; }
      hsout[((size_t)b * T + t) * 512 + jcol] = inr ? hn : 0.f;
      hout[(size_t)b * 512 + jcol] = h_r;
      gbarN(barS, epS, sbase, 128); epS++;   // seq-local step barrier
    }
  }
}

// ---------------- persistent match mega-kernel: 512 threads, 64 steps x {P1,P2,P3} ----------------
// LDS: B1 [10][1024] 40KB persistent | DYN 24KB shared by phase:
//   P1: AL1 [2 kh][4 k4][128 b] f4 (16KB) + P1P partials (5KB)
//   P2: q/we/e/alpha scratch
//   P3: W3 [8][512] (16KB, restaged per step) + AL3 [2][2][128] f4 (8KB, P3P aliases)
__global__ __launch_bounds__(512, 2) void k_match_mega(float* __restrict__ ws,
                                                       const int* __restrict__ hlen) {
  __shared__ float smem[16384];  // 64 KB
  float* B1 = smem;              // [10][1024]
  float* DYN = smem + 10240;     // 6144 floats
  float4* AL1 = (float4*)DYN;               // P1 A-tile
  float* P1P = DYN + 4096;                  // P1 partials [2*128][5]
  float* W3 = DYN;                          // P3 weights [8][512]
  float4* AL3 = (float4*)(DYN + 4096);      // P3 A-tile
  float* P3P = DYN + 4096;                  // P3 partials (alias AL3, synced)
  float* q_lds = DYN; float* we_lds = DYN + 512; float* e_part = DYN + 1024;
  float* e_lds = DYN + 1536; float* alpha_lds = DYN + 1664; float* red_s = DYN + 1792;

  const int tid = threadIdx.x;
  const int bid = blockIdx.x;
  float* hm = ws + OFF_HM;
  const float* ht = ws + OFF_HT;
  float* qT = ws + OFF_Q;        // [512 c][128 b]
  float* ghT = ws + OFF_GH;      // [2048 c][128 b]
  float* abuf = ws + OFF_A;
  float* last = ws + OFF_LAST;
  unsigned* barM = (unsigned*)(ws + OFF_BARM);

  // stage persistent B1 (coalesced)
  {
    const float* wb1t = ws + OFF_WB1T + (size_t)bid * 10 * 1024;
    for (int i = tid; i < 10 * 1024; i += 512) B1[i] = wb1t[i];
  }
  const int w = tid >> 6, lane = tid & 63;
  const int h5 = w >> 2;          // P1 col-half (cols 0-4 / 5-9); P3: jh
  const int khh = (w >> 1) & 1;   // K-half
  const int rh = w & 1;
  const int r = rh * 64 + lane;   // batch row
  const int jh = h5;
  const int j3 = bid * 2 + jh;    // P3 hidden col
  // P1 staging (2 float4/thread/chunk)
  const int i0 = tid, i1 = tid + 512;
  const int kh0s = i0 >> 9, b0s = (i0 & 511) >> 2, q0s = i0 & 3;
  const int kh1s = i1 >> 9, b1s = (i1 & 511) >> 2, q1s = i1 & 3;
  const int idx0 = kh0s * 512 + q0s * 128 + b0s;
  const int idx1 = kh1s * 512 + q1s * 128 + b1s;
  // P3 staging (1 float4/thread/chunk)
  const int kh3s = tid >> 8, b3s = (tid & 255) >> 1, q3s = tid & 1;
  const int idx3 = kh3s * 256 + q3s * 128 + b3s;
  float c_reg = 0.f;
  float bmp[4];
#pragma unroll
  for (int g = 0; g < 4; g++) bmp[g] = ws[OFF_BM + g * 512 + j3];
  const int hl = hlen[r];
  int ep = 1;
  __syncthreads();

  for (int k = 0; k < THh; k++) {
    // ---------- P1: qT + ghT = ([hm | htk] @ WB1T)^T ----------
    {
      float acc1[5] = {0.f, 0.f, 0.f, 0.f, 0.f};
      float4 p0, p1;
      p0 = (kh0s == 0) ? *(const float4*)&hm[(size_t)b0s * 512 + q0s * 4]
                       : *(const float4*)&ht[((size_t)b0s * THh + k) * 512 + q0s * 4];
      p1 = (kh1s == 0) ? *(const float4*)&hm[(size_t)b1s * 512 + q1s * 4]
                       : *(const float4*)&ht[((size_t)b1s * THh + k) * 512 + q1s * 4];
      for (int ch = 0; ch < 32; ch++) {
        __syncthreads();
        AL1[idx0] = p0;
        AL1[idx1] = p1;
        __syncthreads();
        if (ch < 31) {
          int kn = (ch + 1) * 16;
          p0 = (kh0s == 0) ? *(const float4*)&hm[(size_t)b0s * 512 + kn + q0s * 4]
                           : *(const float4*)&ht[((size_t)b0s * THh + k) * 512 + kn + q0s * 4];
          p1 = (kh1s == 0) ? *(const float4*)&hm[(size_t)b1s * 512 + kn + q1s * 4]
                           : *(const float4*)&ht[((size_t)b1s * THh + k) * 512 + kn + q1s * 4];
        }
        const int kc = ch * 16;
        const int cb = h5 * 5;
        const int kbase = khh * 512 + kc;
#pragma unroll
        for (int kk4 = 0; kk4 < 4; kk4++) {
          float4 av = AL1[khh * 512 + kk4 * 128 + r];
#pragma unroll
          for (int cc = 0; cc < 5; cc++) {
            float4 bv = *(float4*)&B1[(cb + cc) * 1024 + kbase + kk4 * 4];  // wave-uniform
            acc1[cc] += av.x * bv.x + av.y * bv.y + av.z * bv.z + av.w * bv.w;
          }
        }
      }
      __syncthreads();
      if (khh == 1) {
#pragma unroll
        for (int cc = 0; cc < 5; cc++) P1P[((size_t)h5 * 128 + r) * 5 + cc] = acc1[cc];
      }
      __syncthreads();
      if (khh == 0) {
        const int cbase = bid * 10 + h5 * 5;
#pragma unroll
        for (int cc = 0; cc < 5; cc++) {
          float val = acc1[cc] + P1P[((size_t)h5 * 128 + r) * 5 + cc];
          int c = cbase + cc;
          if (c < 512) qT[(size_t)c * 128 + r] = val;       // coalesced over r
          else ghT[(size_t)(c - 512) * 128 + r] = val;
        }
      }
    }
    gbarN(barM, ep, 0, 256); ep++;
    // ---------- P2: attention (blocks 0..127, one per batch row) ----------
    if (bid < 128) {
      const int b = bid;
      const float* Wsb = ws + OFF_WSM;
      const float* hs = ws + OFF_HS;
      const float* wef = ws + OFF_WEF;
      q_lds[tid] = qT[(size_t)tid * 128 + b];
      we_lds[tid] = wef[tid];
      __syncthreads();
      {
        int t2 = tid >> 2;
        int gbase = (tid & 3) * 128;
        const float* wsrow = Wsb + ((size_t)b * TPp + t2) * 512 + gbase;
        float s = 0.f;
        for (int ii = 0; ii < 128; ii += 4) {
          float4 wv = *(const float4*)(wsrow + ii);
          float4 qv = *(float4*)&q_lds[gbase + ii];
          float4 ev = *(float4*)&we_lds[gbase + ii];
          s += tanh_f(wv.x + qv.x) * ev.x + tanh_f(wv.y + qv.y) * ev.y +
               tanh_f(wv.z + qv.z) * ev.z + tanh_f(wv.w + qv.w) * ev.w;
        }
        e_part[tid] = s;
      }
      __syncthreads();
      if (tid < 128)
        e_lds[tid] = e_part[tid * 4] + e_part[tid * 4 + 1] + e_part[tid * 4 + 2] + e_part[tid * 4 + 3];
      __syncthreads();
      if (tid < 64) {
        float m = fmaxf(e_lds[tid], e_lds[tid + 64]);
        for (int off = 32; off > 0; off >>= 1) m = fmaxf(m, __shfl_down(m, off));
        if (tid == 0) red_s[0] = m;
      }
      __syncthreads();
      if (tid < 128) alpha_lds[tid] = __expf(e_lds[tid] - red_s[0]);
      __syncthreads();
      if (tid < 64) {
        float s = alpha_lds[tid] + alpha_lds[tid + 64];
        for (int off = 32; off > 0; off >>= 1) s += __shfl_down(s, off);
        if (tid == 0) red_s[1] = 1.f / s;
      }
      __syncthreads();
      {
        float inv = red_s[1];
        float a0 = 0.f;
        const float* hsb = hs + (size_t)b * TPp * 512 + tid;
        for (int t2 = 0; t2 < TPp; t2++) a0 += alpha_lds[t2] * hsb[(size_t)t2 * 512];
        abuf[(size_t)b * 512 + tid] = a0 * inv;
      }
    }
    gbarN(barM, ep, 0, 256); ep++;
    // ---------- P3: a @ WIAT + ghT + bm -> cell update ----------
    {
      // stage W3 (clobbered by P1/P2 scratch each step)
      const float* wiat = ws + OFF_WIA + (size_t)bid * 8 * 512;
#pragma unroll
      for (int s = 0; s < 8; s++) W3[tid + s * 512] = wiat[tid + s * 512];
      float acc3[4] = {0.f, 0.f, 0.f, 0.f};
      float4 p3 = *(const float4*)&abuf[(size_t)b3s * 512 + kh3s * 256 + q3s * 4];
      for (int ch = 0; ch < 32; ch++) {
        __syncthreads();
        AL3[idx3] = p3;
        __syncthreads();
        if (ch < 31) {
          int kn = (ch + 1) * 8;
          p3 = *(const float4*)&abuf[(size_t)b3s * 512 + kh3s * 256 + kn + q3s * 4];
        }
        const int kc = ch * 8;
#pragma unroll
        for (int kk4 = 0; kk4 < 2; kk4++) {
          float4 av = AL3[khh * 256 + kk4 * 128 + r];
#pragma unroll
          for (int g = 0; g < 4; g++) {
            float4 wv = *(float4*)&W3[(jh * 4 + g) * 512 + khh * 256 + kc + kk4 * 4];  // uniform
            acc3[g] += av.x * wv.x + av.y * wv.y + av.z * wv.z + av.w * wv.w;
          }
        }
      }
      __syncthreads();
      if (khh == 1) {
#pragma unroll
        for (int g = 0; g < 4; g++) P3P[((size_t)jh * 128 + r) * 4 + g] = acc3[g];
      }
      __syncthreads();
      if (khh == 0) {
        float gi = acc3[0] + P3P[((size_t)jh * 128 + r) * 4 + 0] + ghT[(size_t)(j3 * 4 + 0) * 128 + r] + bmp[0];
        float gf = acc3[1] + P3P[((size_t)jh * 128 + r) * 4 + 1] + ghT[(size_t)(j3 * 4 + 1) * 128 + r] + bmp[1];
        float gg = acc3[2] + P3P[((size_t)jh * 128 + r) * 4 + 2] + ghT[(size_t)(j3 * 4 + 2) * 128 + r] + bmp[2];
        float go = acc3[3] + P3P[((size_t)jh * 128 + r) * 4 + 3] + ghT[(size_t)(j3 * 4 + 3) * 128 + r] + bmp[3];
        float iv = sigmf(gi), fv = sigmf(gf), gv = tanh_f(gg), ov = sigmf(go);
        float cn = fv * c_reg + iv * gv;
        float hn = ov * tanh_f(cn);
        c_reg = cn;
        hm[(size_t)r * 512 + j3] = hn;
        if (k == hl - 1) last[(size_t)r * 512 + j3] = hn;
      }
    }
    gbarN(barM, ep, 0, 256); ep++;
  }
}

// ---------------- FC epilogue ----------------
__global__ __launch_bounds__(256) void k_fc(const float* __restrict__ ws, const float* __restrict__ Wfc,
                                            const float* __restrict__ bfc, float* __restrict__ out) {
  int idx = blockIdx.x * 256 + threadIdx.x;
  if (idx >= BB * 3) return;
  int b = idx / 3, o = idx - b * 3;
  const float* lrow = ws + OFF_LAST + (size_t)b * 512;
  const float* wrow = Wfc + (size_t)o * 512;
  float acc = bfc[o];
  for (int h = 0; h < 512; h++) acc += lrow[h] * wrow[h];
  out[idx] = acc;
}

extern "C" void kernel_launch(void* const* d_in, const int* in_sizes, int n_in, void* d_out,
                              int out_size, void* d_ws, size_t ws_size, hipStream_t stream) {
  const int* premise = (const int*)d_in[0];
  const int* plen = (const int*)d_in[1];
  const int* hyp = (const int*)d_in[2];
  const int* hlen = (const int*)d_in[3];
  const float* emb = (const float*)d_in[4];
  const float* Wih_p = (const float*)d_in[5];
  const float* Whh_p = (const float*)d_in[6];
  const float* bih_p = (const float*)d_in[7];
  const float* bhh_p = (const float*)d_in[8];
  const float* Wih_h = (const float*)d_in[9];
  const float* Whh_h = (const float*)d_in[10];
  const float* bih_h = (const float*)d_in[11];
  const float* bhh_h = (const float*)d_in[12];
  const float* Wih_m = (const float*)d_in[13];
  const float* Whh_m = (const float*)d_in[14];
  const float* bih_m = (const float*)d_in[15];
  const float* bhh_m = (const float*)d_in[16];
  const float* w_e = (const float*)d_in[17];
  const float* W_s = (const float*)d_in[18];
  const float* W_t = (const float*)d_in[19];
  const float* W_m = (const float*)d_in[20];
  const float* W_fc = (const float*)d_in[21];
  const float* b_fc = (const float*)d_in[22];
  float* ws = (float*)d_ws;
  float* out = (float*)d_out;

  if (ws_size < WS_FLOATS * sizeof(float)) {
    float mb = (float)((double)ws_size / (1024.0 * 1024.0));
    k_diag<<<dim3(6), dim3(64), 0, stream>>>(out, mb);
    return;
  }

  // K0: weight prep + state/counter zero
  {
    size_t total = 2 * SZ_WIHT + 2 * (size_t)512 * 2048 + (size_t)2560 * 1024 +
                   (size_t)2048 * 512 + 512 + 2048 + 393216 + 131072 + 11824;
    int nb = (int)((total + 255) / 256);
    k_prep<<<dim3(nb), dim3(256), 0, stream>>>(ws, Wih_p, bih_p, bhh_p, Wih_h, bih_h, bhh_h,
                                               Whh_p, Whh_h, Whh_m, Wih_m, bih_m, bhh_m,
                                               W_m, W_t, w_e);
  }
  // persistent LSTM (all 128 steps, split slot-barriers)
  {
    void* args[] = {(void*)&ws, (void*)&premise, (void*)&hyp, (void*)&plen, (void*)&hlen, (void*)&emb};
    hipError_t e = hipLaunchCooperativeKernel((const void*)k_lstm_mega, dim3(256), dim3(512),
                                              args, 0, stream);
    if (e != hipSuccess)
      k_lstm_mega<<<dim3(256), dim3(512), 0, stream>>>(ws, premise, hyp, plen, hlen, emb);
  }
  // Ws = HS @ W_s^T (WSM region free again)
  k_gemm<<<dim3(256 * 8), dim3(256), 0, stream>>>(ws + OFF_HS, W_s, 512, 512, 512,
                                                  ws + OFF_WSM, 8);
  // persistent match loop (64 steps, 3 slot-barriers/step)
  {
    void* args[] = {(void*)&ws, (void*)&hlen};
    hipError_t e = hipLaunchCooperativeKernel((const void*)k_match_mega, dim3(256), dim3(512),
                                              args, 0, stream);
    if (e != hipSuccess)
      k_match_mega<<<dim3(256), dim3(512), 0, stream>>>(ws, hlen);
  }
  // FC epilogue
  k_fc<<<dim3(2), dim3(256), 0, stream>>>(ws, W_fc, b_fc, out);
}